// Round 11
// baseline (89.984 us; speedup 1.0000x reference)
//
#include <hip/hip_runtime.h>

// FlowLenia single step — MFMA implicit-GEMM convolution (f16), fused flow+RT.
// A:[4,1,256,256,3] f32, Kn:[256,256,12] f32, m/s/h:[12], c0/c1 = arange(12)%3.
// out nA:[4,1,256,256,3] f32.
//
// Conv (r8 loop + two-phase staging): 256-thr blocks, 4 waves (one y-octet
// each), 8-deep in-place B ring, dual acc chains. A halo staged in TWO phases
// (di<=0 rows, then di>0 rows) -> LDS 25.5 KB -> 3 blocks/CU all-resident.

typedef _Float16 f16;
typedef __attribute__((ext_vector_type(8))) _Float16 half8;
typedef __attribute__((ext_vector_type(16))) float f32x16;

#define RMAX 44
#define NROWS 89                  // 2*RMAX+1
#define NDMAX 8
#define NFRAG (3*NROWS*NDMAX)     // real fragments; slot NFRAG = zeros
#define ST 168                    // LDS row stride (f16), 21 half8 chunks
#define PROWS 76                  // RMAX + 32 rows per phase
#define SCHED_STRIDE 1024
#define KTHR 1e-7f

// ---------------- kernel 1: per-(c,di) dj bounds + per-row radius ----------------
__global__ __launch_bounds__(128) void lenia_meta(const float* __restrict__ Kn,
                                                  int2* __restrict__ meta,
                                                  int* __restrict__ rowr) {
    int blk = blockIdx.x;                 // 3*NROWS
    int c = blk / NROWS, ri = blk - c * NROWS;
    int di = ri - RMAX;
    int t = threadIdx.x;
    int dj = t - RMAX;
    int act = 0;
    if (t < NROWS) {
        size_t base = (size_t)(((di + 128) << 8) | (dj + 128)) * 12 + c;
        float k0 = Kn[base], k1 = Kn[base + 3], k2 = Kn[base + 6], k3 = Kn[base + 9];
        act = (fmaxf(fmaxf(k0, k1), fmaxf(k2, k3)) > KTHR) ? 1 : 0;
    }
    __shared__ int smn[128], smx[128];
    smn[t] = act ? dj : 1000;
    smx[t] = act ? dj : -1000;
    __syncthreads();
    for (int s = 64; s > 0; s >>= 1) {
        if (t < s) { smn[t] = min(smn[t], smn[t + s]); smx[t] = max(smx[t], smx[t + s]); }
        __syncthreads();
    }
    if (t == 0) {
        int jmn = smn[0], jmx = smx[0];
        if (jmx < jmn) { meta[blk] = make_int2(1, 0); rowr[blk] = 0; }
        else {
            meta[blk] = make_int2(jmn, jmx);
            rowr[blk] = max(abs(di), max(abs(jmn), abs(jmx)));
        }
    }
}

// ------- kernel 2: two-phase flat schedule (phase-local LDS row offsets) + radii -------
__global__ __launch_bounds__(128) void lenia_sched(const int2* __restrict__ meta,
                                                   const int* __restrict__ rowr,
                                                   int2* __restrict__ meta2,
                                                   unsigned int* __restrict__ sched,
                                                   int2* __restrict__ nsched,
                                                   int* __restrict__ radii) {
    int c = blockIdx.x;                   // 3 blocks
    int t = threadIdx.x;
    __shared__ int pre[NROWS], nds[NROWS], rmx[128];
    __shared__ int s_R, s_ns0, s_tot0;
    int nd = 0, d0 = 0;
    if (t < NROWS) {
        int2 bm = meta[c * NROWS + t];
        if (bm.y >= bm.x) {
            d0 = ((bm.x - 7) >> 3) << 3;          // delta0 <= jmn-7, mult of 8
            nd = ((bm.y + 7 - d0) >> 4) + 1;      // cover dj' = jmx for sy up to 7
        }
        meta2[c * NROWS + t] = make_int2(d0, nd);
        nds[t] = nd;
    }
    rmx[t] = (t < NROWS) ? rowr[c * NROWS + t] : 0;
    __syncthreads();
    for (int s = 64; s > 0; s >>= 1) {
        if (t < s) rmx[t] = max(rmx[t], rmx[t + s]);
        __syncthreads();
    }
    if (t == 0) {
        int R = max(1, min(rmx[0], RMAX));
        radii[c] = rmx[0];
        s_R = R;
        int acc = 0;
        for (int i = 0; i < NROWS; ++i) { pre[i] = acc; acc += nds[i]; }
        int tot0 = pre[RMAX] + nds[RMAX];         // entries with di <= 0 (t <= RMAX)
        int tot1 = acc - tot0;
        int ns0 = (tot0 + 7) & ~7;
        int ns1 = (tot1 + 7) & ~7;
        s_ns0 = ns0; s_tot0 = tot0;
        nsched[c] = make_int2(ns0, ns1);
        unsigned int* sc = sched + c * SCHED_STRIDE;
        unsigned int pad0 = (unsigned int)NFRAG | ((unsigned int)(R * ST + 128) << 12);
        unsigned int pad1 = (unsigned int)NFRAG | (128u << 12);
        for (int i = tot0; i < ns0; ++i) sc[i] = pad0;               // phase-0 pads
        for (int i = ns0 + tot1; i < ns0 + ns1 + 16; ++i) sc[i] = pad1; // phase-1 pads
    }
    __syncthreads();
    if (t < NROWS && nd > 0) {
        int R = s_R, ns0 = s_ns0, tot0 = s_tot0;
        int di = t - RMAX;
        int base   = (t <= RMAX) ? pre[t] : ns0 + (pre[t] - tot0);
        int rowoff = (t <= RMAX) ? (di + R) * ST : (di - 1) * ST;    // phase-local row
        for (int i = 0; i < nd; ++i) {
            int delta = d0 + 16 * i;
            unsigned int off = (unsigned int)(rowoff + delta + 128); // 14 bits
            sched[c * SCHED_STRIDE + base + i] =
                (unsigned int)((c * NROWS + t) * NDMAX + i) | (off << 12);
        }
    }
}

// ------------- kernel 3: transpose Kn -> Ktr[12][65536] f16, A -> Atr[12][65536] f16 -------------
__global__ __launch_bounds__(256) void lenia_trans(const float* __restrict__ Kn,
                                                   const float* __restrict__ A,
                                                   f16* __restrict__ Ktr,
                                                   f16* __restrict__ Atr) {
    int blk = blockIdx.x, tid = threadIdx.x;
    if (blk < 256) {
        int gid = blk * 256 + tid;
        const float4* kp = (const float4*)(Kn + (size_t)gid * 12);
        float4 v0 = kp[0], v1 = kp[1], v2 = kp[2];
        Ktr[0 * 65536 + gid]  = (f16)v0.x;  Ktr[1 * 65536 + gid]  = (f16)v0.y;
        Ktr[2 * 65536 + gid]  = (f16)v0.z;  Ktr[3 * 65536 + gid]  = (f16)v0.w;
        Ktr[4 * 65536 + gid]  = (f16)v1.x;  Ktr[5 * 65536 + gid]  = (f16)v1.y;
        Ktr[6 * 65536 + gid]  = (f16)v1.z;  Ktr[7 * 65536 + gid]  = (f16)v1.w;
        Ktr[8 * 65536 + gid]  = (f16)v2.x;  Ktr[9 * 65536 + gid]  = (f16)v2.y;
        Ktr[10 * 65536 + gid] = (f16)v2.z;  Ktr[11 * 65536 + gid] = (f16)v2.w;
    } else {
        int px = (blk - 256) * 256 + tid;        // 0..262143
        int b = px >> 16, rem = px & 65535;
        const float* ap = A + (size_t)px * 3;
        Atr[(size_t)(b * 3 + 0) * 65536 + rem] = (f16)ap[0];
        Atr[(size_t)(b * 3 + 1) * 65536 + rem] = (f16)ap[1];
        Atr[(size_t)(b * 3 + 2) * 65536 + rem] = (f16)ap[2];
    }
}

// ---------------- kernel 4: pack B fragments from Ktr (frag-indexed) ----------------
__global__ __launch_bounds__(256) void lenia_bpack(const f16* __restrict__ Ktr,
                                                   const int2* __restrict__ meta2,
                                                   uint4* __restrict__ bpack) {
    int fi = blockIdx.x * 4 + (threadIdx.x >> 6);
    int l = threadIdx.x & 63;
    if (fi > NFRAG) return;
    union { f16 h[8]; uint4 u; } pk;
    if (fi == NFRAG) {
        pk.u = make_uint4(0, 0, 0, 0);
        bpack[(size_t)fi * 64 + l] = pk.u;
        return;
    }
    int c = fi / (NROWS * NDMAX);
    int rem = fi - c * (NROWS * NDMAX);
    int ri = rem >> 3, didx = rem & 7;
    int di = ri - RMAX;
    int delta = meta2[c * NROWS + ri].x + 16 * didx;
    int q = (l & 31) >> 3, sy = l & 7, g = l >> 5;
    int dj0 = delta + 8 * g - sy;         // row-local, in-bounds
    const f16* src = Ktr + (size_t)(c + 3 * q) * 65536 + ((di + 128) << 8) + (dj0 + 128);
    #pragma unroll
    for (int j = 0; j < 8; ++j) pk.h[j] = src[j];
    bpack[(size_t)fi * 64 + l] = pk.u;
}

// ---------------- kernel 5: MFMA conv (two-phase) + growth -> Uc ----------------
// 4 waves; wave wid owns y-octet wid over ALL entries. Phase 0: di<=0 rows,
// phase 1: di>0 rows; 25.5 KB LDS -> 3 blocks/CU resident. r8 ring/acc body.
__global__ __launch_bounds__(256) void lenia_conv(
        const f16* __restrict__ Atr, const uint4* __restrict__ bpack,
        const unsigned int* __restrict__ sched, const int2* __restrict__ nsched,
        const int* __restrict__ radii,
        const float* __restrict__ mp, const float* __restrict__ sp,
        const float* __restrict__ hp, f16* __restrict__ Uc) {
    extern __shared__ f16 smh[];

    const int tid = threadIdx.x;
    const int bc = blockIdx.y;
    const int b = bc / 3, c = bc - b * 3;
    const int x0 = (blockIdx.x >> 3) << 5;
    const int y0 = (blockIdx.x & 7) << 5;

    const int R = __builtin_amdgcn_readfirstlane(min(max(radii[c], 1), RMAX));
    const int R8 = (R + 7) & ~7;
    const int colbase = y0 - R8 - 16;     // mult of 8
    const f16* Ap = Atr + (size_t)(b * 3 + c) * 65536;

    const int lane = tid & 63, wid = tid >> 6;    // wid 0..3, octet per wave
    const int m = lane & 31, g = lane >> 5;
    const int abase = m * ST + 8 * wid + R8 + 16 + 8 * g - 128;

    const int2 nsv = nsched[c];
    const int ns0 = __builtin_amdgcn_readfirstlane(nsv.x);
    const int ns1 = __builtin_amdgcn_readfirstlane(nsv.y);
    const unsigned int* schedC = sched + c * SCHED_STRIDE;

    f32x16 accE, accO;
    #pragma unroll
    for (int r = 0; r < 16; ++r) { accE[r] = 0.f; accO[r] = 0.f; }

    for (int phase = 0; phase < 2; ++phase) {
        const int rowBase = phase ? (x0 + 1) : (x0 - R);
        const int nrows   = phase ? (R + 31) : (R + 32);
        const int nsP     = phase ? ns1 : ns0;
        const unsigned int* sW = phase ? (schedC + ns0) : schedC;

        if (phase) __syncthreads();       // phase-0 readers done before overwrite
        {   // staging: half8 (16B) chunks; 21 chunks/row
            int nchunk = nrows * 21;
            int tr = tid / 21, rem = tid - tr * 21;
            for (int ci = tid; ci < nchunk; ci += 256) {
                int gi = (rowBase + tr) & 255;
                int gj = (colbase + rem * 8) & 255;   // mult of 8, no wrap inside
                *(half8*)(smh + tr * ST + rem * 8) = *(const half8*)(Ap + (gi << 8) + gj);
                tr += 12; rem += 4;                   // +256 chunks = 12*21 + 4
                if (rem >= 21) { rem -= 21; ++tr; }
            }
        }
        __syncthreads();

        unsigned int eq[8];
        uint4 bq[8];
        #pragma unroll
        for (int j = 0; j < 8; ++j) {
            eq[j] = sW[j];
            bq[j] = bpack[(size_t)(eq[j] & 4095u) * 64 + lane];
        }

        for (int it = 0; it < nsP; it += 8) {
            #pragma unroll
            for (int j = 0; j < 8; j += 2) {
                {   // even entry -> accE
                    half8 av = *(const half8*)(smh + abase + (int)(eq[j] >> 12));
                    union { uint4 u; half8 h; } bb; bb.u = bq[j];
                    accE = __builtin_amdgcn_mfma_f32_32x32x16_f16(av, bb.h, accE, 0, 0, 0);
                    unsigned int ne = sW[it + 8 + j];
                    eq[j] = ne;
                    bq[j] = bpack[(size_t)(ne & 4095u) * 64 + lane];
                }
                {   // odd entry -> accO (independent chain)
                    half8 av = *(const half8*)(smh + abase + (int)(eq[j + 1] >> 12));
                    union { uint4 u; half8 h; } bb; bb.u = bq[j + 1];
                    accO = __builtin_amdgcn_mfma_f32_32x32x16_f16(av, bb.h, accO, 0, 0, 0);
                    unsigned int ne = sW[it + 9 + j];
                    eq[j + 1] = ne;
                    bq[j + 1] = bpack[(size_t)(ne & 4095u) * 64 + lane];
                }
            }
        }
    }

    // growth + sum over q (lanes l, l^8, l^16) -> Uc (f16)
    const int q = (lane & 31) >> 3, sy = lane & 7;
    const float mq = mp[c + 3 * q];
    const float sq = sp[c + 3 * q];
    const float hq = hp[c + 3 * q];
    const float i2s = 1.f / (2.f * sq * sq);
    #pragma unroll
    for (int r = 0; r < 16; ++r) {
        float d = (accE[r] + accO[r]) - mq;
        float gg = (2.f * expf(-d * d * i2s) - 1.f) * hq;
        gg += __shfl_xor(gg, 8);
        gg += __shfl_xor(gg, 16);
        if ((lane & 24) == 0) {
            int row = (r & 3) + ((r >> 2) << 3) + (g << 2);
            Uc[((size_t)(b << 16) + ((x0 + row) << 8) + (y0 + 8 * wid + sy)) * 3 + c] = (f16)gg;
        }
    }
}

// ------------- kernel 6: fused sobel+flow+mus + reintegration tracking -------------
#define FTW 44
#define FSW 45
#define PLH (FSW * FTW)           // 1980 elems per plane
__global__ __launch_bounds__(256) void lenia_flowrt(
        const float* __restrict__ A, const f16* __restrict__ Uc,
        float* __restrict__ out) {
    extern __shared__ char fraw[];
    f16*    ucp = (f16*)fraw;                    // [3][PLH]
    f16*    atp = (f16*)(fraw + 3 * PLH * 2);    // [3][PLH]
    float4* mqp = (float4*)(fraw + 6 * PLH * 2); // [3][PLH]  (dx, dy, a, 0)

    int b = blockIdx.y, t = blockIdx.x;          // 64 tiles of 32x32
    int x0 = (t >> 3) << 5, y0 = (t & 7) << 5;
    const float* Ab = A  + ((size_t)b << 16) * 3;
    const f16*   Ub = Uc + ((size_t)b << 16) * 3;

    for (int idx = threadIdx.x; idx < FTW * FTW; idx += 256) {
        int si = idx / FTW, sj = idx - si * FTW;
        int gi = (x0 - 6 + si) & 255, gj = (y0 - 6 + sj) & 255;
        size_t p = (size_t)((gi << 8) + gj) * 3;
        int o = si * FSW + sj;
        ucp[o] = Ub[p]; ucp[PLH + o] = Ub[p + 1]; ucp[2 * PLH + o] = Ub[p + 2];
        atp[o] = (f16)Ab[p]; atp[PLH + o] = (f16)Ab[p + 1]; atp[2 * PLH + o] = (f16)Ab[p + 2];
    }
    __syncthreads();

    // mus phase: 42x42 cells
    for (int idx = threadIdx.x; idx < 42 * 42; idx += 256) {
        int ci = idx / 42, cj = idx - ci * 42;
        int si = ci + 1, sj = cj + 1;
        int o = si * FSW + sj;
        int vx = x0 - 6 + si, vy = y0 - 6 + sj;
        float sx = (vx < 0 || vx > 255) ? 1e7f : 0.f;
        float syv = (vy < 0 || vy > 255) ? 1e7f : 0.f;

        float as[3][3];
        #pragma unroll
        for (int i = 0; i < 3; ++i)
            #pragma unroll
            for (int j = 0; j < 3; ++j) {
                int oo = o + (i - 1) * FSW + (j - 1);
                as[i][j] = (float)atp[oo] + (float)atp[PLH + oo] + (float)atp[2 * PLH + oo];
            }
        float gxA = ((as[2][0] + 2.f * as[2][1] + as[2][2])
                   - (as[0][0] + 2.f * as[0][1] + as[0][2])) * 0.125f;
        float gyA = ((as[0][2] + 2.f * as[1][2] + as[2][2])
                   - (as[0][0] + 2.f * as[1][0] + as[2][0])) * 0.125f;

        #pragma unroll
        for (int c = 0; c < 3; ++c) {
            const f16* up = ucp + c * PLH;
            float u00 = up[o - FSW - 1], u01 = up[o - FSW], u02 = up[o - FSW + 1];
            float u10 = up[o - 1],                        u12 = up[o + 1];
            float u20 = up[o + FSW - 1], u21 = up[o + FSW], u22 = up[o + FSW + 1];
            float gx = ((u20 + 2.f * u21 + u22) - (u00 + 2.f * u01 + u02)) * 0.125f;
            float gy = ((u02 + 2.f * u12 + u22) - (u00 + 2.f * u10 + u20)) * 0.125f;
            float a = (float)atp[c * PLH + o];
            float alpha = fminf(a * a, 1.f);
            float Fx = gx * (1.f - alpha) - gxA * alpha;
            float Fy = gy * (1.f - alpha) - gyA * alpha;
            float dx = fminf(fmaxf(0.2f * Fx, -4.35f), 4.35f) + sx;
            float dy = fminf(fmaxf(0.2f * Fy, -4.35f), 4.35f) + syv;
            mqp[c * PLH + o] = make_float4(dx, dy, a, 0.f);
        }
    }
    __syncthreads();

    // gather: thread = (x col tx, y quad tyg)
    int tx = threadIdx.x & 31, tyg = threadIdx.x >> 5;
    int ty0 = tyg << 2;
    float acc[3][4] = {};

    for (int dxs = 0; dxs < 11; ++dxs) {
        float fdx = (float)(5 - dxs);
        int rowb = (tx + 1 + dxs) * FSW + (ty0 + 1);
        #pragma unroll
        for (int sjj = 0; sjj < 14; ++sjj) {
            float fdy = (float)(5 - sjj);
            #pragma unroll
            for (int c = 0; c < 3; ++c) {
                float4 qv = mqp[c * PLH + rowb + sjj];
                float wx = fminf(fmaxf(1.15f - fabsf(fdx - qv.x), 0.f), 1.f);
                float awx = qv.z * wx;
                float e0 = fdy - qv.y;
                acc[c][0] = fmaf(awx, fminf(fmaxf(1.15f - fabsf(e0), 0.f), 1.f), acc[c][0]);
                acc[c][1] = fmaf(awx, fminf(fmaxf(1.15f - fabsf(e0 + 1.f), 0.f), 1.f), acc[c][1]);
                acc[c][2] = fmaf(awx, fminf(fmaxf(1.15f - fabsf(e0 + 2.f), 0.f), 1.f), acc[c][2]);
                acc[c][3] = fmaf(awx, fminf(fmaxf(1.15f - fabsf(e0 + 3.f), 0.f), 1.f), acc[c][3]);
            }
        }
    }
    const float inv = 1.0f / 1.69f;   // 1/(4*sigma^2)
    #pragma unroll
    for (int tt = 0; tt < 4; ++tt) {
        size_t o = ((size_t)(b << 16) + ((x0 + tx) << 8) + (y0 + ty0 + tt)) * 3;
        out[o]     = acc[0][tt] * inv;
        out[o + 1] = acc[1][tt] * inv;
        out[o + 2] = acc[2][tt] * inv;
    }
}

extern "C" void kernel_launch(void* const* d_in, const int* in_sizes, int n_in,
                              void* d_out, int out_size, void* d_ws, size_t ws_size,
                              hipStream_t stream) {
    const float* A  = (const float*)d_in[0];
    const float* Kn = (const float*)d_in[1];
    const float* m  = (const float*)d_in[2];
    const float* s  = (const float*)d_in[3];
    const float* h  = (const float*)d_in[4];

    char* ws = (char*)d_ws;
    int*          radii = (int*)ws;                        // 16 B
    int2*         nschd = (int2*)(ws + 16);                // 24 B
    int*          rowr  = (int*)(ws + 64);                 // 267*4
    int2*         meta  = (int2*)(ws + 2048);              // 267*8
    int2*         meta2 = (int2*)(ws + 8192);              // 267*8
    unsigned int* sched = (unsigned int*)(ws + 16384);     // 12 KB
    f16*          Ktr   = (f16*)(ws + 32768);              // 1.57 MB (dead after bpack)
    f16*          Atr   = (f16*)(ws + 1605632);            // 1.57 MB
    uint4*        bpack = (uint4*)(ws + 3178496);          // 2.19 MB -> ends 5.37 MB
    f16*          Uc    = (f16*)(ws + 32768);              // 1.57 MB, OVERLAYS dead Ktr

    lenia_meta<<<3 * NROWS, 128, 0, stream>>>(Kn, meta, rowr);
    lenia_sched<<<3, 128, 0, stream>>>(meta, rowr, meta2, sched, nschd, radii);
    lenia_trans<<<1280, 256, 0, stream>>>(Kn, A, Ktr, Atr);
    lenia_bpack<<<(NFRAG + 4) / 4, 256, 0, stream>>>(Ktr, meta2, bpack);
    lenia_conv<<<dim3(64, 12), 256, PROWS * ST * sizeof(f16), stream>>>(
        Atr, bpack, sched, nschd, radii, m, s, h, Uc);
    lenia_flowrt<<<dim3(64, 4), 256, (6 * PLH * 2) + (3 * PLH * 16), stream>>>(
        A, Uc, (float*)d_out);
}

// Round 12
// 74.946 us; speedup vs baseline: 1.2007x; 1.2007x over previous
//
#include <hip/hip_runtime.h>

// FlowLenia single step — MFMA implicit-GEMM convolution (f16), fused flow+RT.
// A:[4,1,256,256,3] f32, Kn:[256,256,12] f32, m/s/h:[12], c0/c1 = arange(12)%3.
// out nA:[4,1,256,256,3] f32.
//
// Conv = r8 structure (256 thr, 4 waves one y-octet each, dual acc chains)
// with a 16-deep IN-PLACE B ring (B-load lead ~560cyc > L2 latency).
// flowrt split per-channel (grid 64x12) reading f16 Atr planes.

typedef _Float16 f16;
typedef __attribute__((ext_vector_type(8))) _Float16 half8;
typedef __attribute__((ext_vector_type(16))) float f32x16;

#define RMAX 44
#define NROWS 89                  // 2*RMAX+1
#define NDMAX 8
#define NFRAG (3*NROWS*NDMAX)     // real fragments; slot NFRAG = zeros
#define ST 168                    // LDS row stride (f16), 21 half8 chunks
#define TROWS 120                 // 32 + 2*RMAX
#define SCHED_STRIDE 1024
#define KTHR 1e-7f

// ---------------- kernel 1: per-(c,di) dj bounds + per-row radius ----------------
__global__ __launch_bounds__(128) void lenia_meta(const float* __restrict__ Kn,
                                                  int2* __restrict__ meta,
                                                  int* __restrict__ rowr) {
    int blk = blockIdx.x;                 // 3*NROWS
    int c = blk / NROWS, ri = blk - c * NROWS;
    int di = ri - RMAX;
    int t = threadIdx.x;
    int dj = t - RMAX;
    int act = 0;
    if (t < NROWS) {
        size_t base = (size_t)(((di + 128) << 8) | (dj + 128)) * 12 + c;
        float k0 = Kn[base], k1 = Kn[base + 3], k2 = Kn[base + 6], k3 = Kn[base + 9];
        act = (fmaxf(fmaxf(k0, k1), fmaxf(k2, k3)) > KTHR) ? 1 : 0;
    }
    __shared__ int smn[128], smx[128];
    smn[t] = act ? dj : 1000;
    smx[t] = act ? dj : -1000;
    __syncthreads();
    for (int s = 64; s > 0; s >>= 1) {
        if (t < s) { smn[t] = min(smn[t], smn[t + s]); smx[t] = max(smx[t], smx[t + s]); }
        __syncthreads();
    }
    if (t == 0) {
        int jmn = smn[0], jmx = smx[0];
        if (jmx < jmn) { meta[blk] = make_int2(1, 0); rowr[blk] = 0; }
        else {
            meta[blk] = make_int2(jmn, jmx);
            rowr[blk] = max(abs(di), max(abs(jmn), abs(jmx)));
        }
    }
}

// ------------- kernel 2: chunk geometry + flat schedule (w/ LDS offsets) + radii -------------
__global__ __launch_bounds__(128) void lenia_sched(const int2* __restrict__ meta,
                                                   const int* __restrict__ rowr,
                                                   int2* __restrict__ meta2,
                                                   unsigned int* __restrict__ sched,
                                                   int* __restrict__ nsched,
                                                   int* __restrict__ radii) {
    int c = blockIdx.x;                   // 3 blocks
    int t = threadIdx.x;
    __shared__ int pre[NROWS], nds[NROWS], rmx[128];
    int nd = 0, d0 = 0;
    if (t < NROWS) {
        int2 bm = meta[c * NROWS + t];
        if (bm.y >= bm.x) {
            d0 = ((bm.x - 7) >> 3) << 3;          // delta0 <= jmn-7, mult of 8
            nd = ((bm.y + 7 - d0) >> 4) + 1;      // cover dj' = jmx for sy up to 7
        }
        meta2[c * NROWS + t] = make_int2(d0, nd);
        nds[t] = nd;
    }
    rmx[t] = (t < NROWS) ? rowr[c * NROWS + t] : 0;
    __syncthreads();
    for (int s = 64; s > 0; s >>= 1) {
        if (t < s) rmx[t] = max(rmx[t], rmx[t + s]);
        __syncthreads();
    }
    __shared__ int tot;
    if (t == 0) {
        radii[c] = rmx[0];
        int acc = 0;
        for (int i = 0; i < NROWS; ++i) { pre[i] = acc; acc += nds[i]; }
        tot = acc;
    }
    __syncthreads();
    if (t < NROWS && nd > 0) {
        int base = pre[t];
        for (int i = 0; i < nd; ++i) {
            int delta = d0 + 16 * i;
            unsigned int off = (unsigned int)(t * ST + delta + 128);   // 14 bits
            sched[c * SCHED_STRIDE + base + i] =
                (unsigned int)((c * NROWS + t) * NDMAX + i) | (off << 12);
        }
    }
    if (t == 0) {
        int ns = (tot + 7) & ~7;
        unsigned int padoff = (unsigned int)(RMAX * ST + 128);
        for (int i = tot; i < ns + 48; ++i)       // pads: zero frag, valid lds addr
            sched[c * SCHED_STRIDE + i] = (unsigned int)NFRAG | (padoff << 12);
        nsched[c] = ns;
    }
}

// ------------- kernel 3: transpose Kn -> Ktr[12][65536] f16, A -> Atr[12][65536] f16 -------------
__global__ __launch_bounds__(256) void lenia_trans(const float* __restrict__ Kn,
                                                   const float* __restrict__ A,
                                                   f16* __restrict__ Ktr,
                                                   f16* __restrict__ Atr) {
    int blk = blockIdx.x, tid = threadIdx.x;
    if (blk < 256) {
        int gid = blk * 256 + tid;
        const float4* kp = (const float4*)(Kn + (size_t)gid * 12);
        float4 v0 = kp[0], v1 = kp[1], v2 = kp[2];
        Ktr[0 * 65536 + gid]  = (f16)v0.x;  Ktr[1 * 65536 + gid]  = (f16)v0.y;
        Ktr[2 * 65536 + gid]  = (f16)v0.z;  Ktr[3 * 65536 + gid]  = (f16)v0.w;
        Ktr[4 * 65536 + gid]  = (f16)v1.x;  Ktr[5 * 65536 + gid]  = (f16)v1.y;
        Ktr[6 * 65536 + gid]  = (f16)v1.z;  Ktr[7 * 65536 + gid]  = (f16)v1.w;
        Ktr[8 * 65536 + gid]  = (f16)v2.x;  Ktr[9 * 65536 + gid]  = (f16)v2.y;
        Ktr[10 * 65536 + gid] = (f16)v2.z;  Ktr[11 * 65536 + gid] = (f16)v2.w;
    } else {
        int px = (blk - 256) * 256 + tid;        // 0..262143
        int b = px >> 16, rem = px & 65535;
        const float* ap = A + (size_t)px * 3;
        Atr[(size_t)(b * 3 + 0) * 65536 + rem] = (f16)ap[0];
        Atr[(size_t)(b * 3 + 1) * 65536 + rem] = (f16)ap[1];
        Atr[(size_t)(b * 3 + 2) * 65536 + rem] = (f16)ap[2];
    }
}

// ---------------- kernel 4: pack B fragments from Ktr (frag-indexed) ----------------
__global__ __launch_bounds__(256) void lenia_bpack(const f16* __restrict__ Ktr,
                                                   const int2* __restrict__ meta2,
                                                   uint4* __restrict__ bpack) {
    int fi = blockIdx.x * 4 + (threadIdx.x >> 6);
    int l = threadIdx.x & 63;
    if (fi > NFRAG) return;
    union { f16 h[8]; uint4 u; } pk;
    if (fi == NFRAG) {
        pk.u = make_uint4(0, 0, 0, 0);
        bpack[(size_t)fi * 64 + l] = pk.u;
        return;
    }
    int c = fi / (NROWS * NDMAX);
    int rem = fi - c * (NROWS * NDMAX);
    int ri = rem >> 3, didx = rem & 7;
    int di = ri - RMAX;
    int delta = meta2[c * NROWS + ri].x + 16 * didx;
    int q = (l & 31) >> 3, sy = l & 7, g = l >> 5;
    int dj0 = delta + 8 * g - sy;         // row-local, in-bounds
    const f16* src = Ktr + (size_t)(c + 3 * q) * 65536 + ((di + 128) << 8) + (dj0 + 128);
    #pragma unroll
    for (int j = 0; j < 8; ++j) pk.h[j] = src[j];
    bpack[(size_t)fi * 64 + l] = pk.u;
}

// ---------------- kernel 5: MFMA conv + growth -> Uc (f16, in ws) ----------------
// r8 structure; 16-deep IN-PLACE B ring (no register shifting).
__global__ __launch_bounds__(256) void lenia_conv(
        const f16* __restrict__ Atr, const uint4* __restrict__ bpack,
        const unsigned int* __restrict__ sched, const int* __restrict__ nsched,
        const int* __restrict__ radii,
        const float* __restrict__ mp, const float* __restrict__ sp,
        const float* __restrict__ hp, f16* __restrict__ Uc) {
    extern __shared__ f16 smh[];

    const int tid = threadIdx.x;
    const int bc = blockIdx.y;
    const int b = bc / 3, c = bc - b * 3;
    const int x0 = (blockIdx.x >> 3) << 5;
    const int y0 = (blockIdx.x & 7) << 5;

    const int R = __builtin_amdgcn_readfirstlane(min(max(radii[c], 1), RMAX));
    const int R8 = (R + 7) & ~7;
    const int colbase = y0 - R8 - 16;     // mult of 8
    const int rows = 32 + 2 * R;
    const f16* Ap = Atr + (size_t)(b * 3 + c) * 65536;

    {   // staging: half8 (16B) chunks; 21 chunks/row
        int nchunk = rows * 21;
        int tr = tid / 21, rem = tid - tr * 21;
        for (int ci = tid; ci < nchunk; ci += 256) {
            int gi = (x0 - R + tr) & 255;
            int gj = (colbase + rem * 8) & 255;   // mult of 8 -> never crosses wrap
            *(half8*)(smh + tr * ST + rem * 8) = *(const half8*)(Ap + (gi << 8) + gj);
            tr += 12; rem += 4;                   // +256 chunks = 12*21 + 4
            if (rem >= 21) { rem -= 21; ++tr; }
        }
    }
    __syncthreads();

    const int lane = tid & 63, wid = tid >> 6;    // wid 0..3, octet per wave
    const int m = lane & 31, g = lane >> 5;
    const int abase = (m + R - RMAX) * ST + 8 * wid + R8 + 16 + 8 * g - 128;

    const unsigned int* sW = sched + c * SCHED_STRIDE;
    const int ns = __builtin_amdgcn_readfirstlane(nsched[c]);

    f32x16 accE, accO;
    #pragma unroll
    for (int r = 0; r < 16; ++r) { accE[r] = 0.f; accO[r] = 0.f; }

    unsigned int eq[16];
    uint4 bq[16];
    #pragma unroll
    for (int j = 0; j < 16; ++j) {
        eq[j] = sW[j];
        bq[j] = bpack[(size_t)(eq[j] & 4095u) * 64 + lane];
    }

    for (int it = 0; it < ns; it += 16) {
        #pragma unroll
        for (int j = 0; j < 16; j += 2) {
            {   // even entry -> accE
                half8 av = *(const half8*)(smh + abase + (int)(eq[j] >> 12));
                union { uint4 u; half8 h; } bb; bb.u = bq[j];
                accE = __builtin_amdgcn_mfma_f32_32x32x16_f16(av, bb.h, accE, 0, 0, 0);
                unsigned int ne = sW[it + 16 + j];
                eq[j] = ne;
                bq[j] = bpack[(size_t)(ne & 4095u) * 64 + lane];
            }
            {   // odd entry -> accO (independent chain)
                half8 av = *(const half8*)(smh + abase + (int)(eq[j + 1] >> 12));
                union { uint4 u; half8 h; } bb; bb.u = bq[j + 1];
                accO = __builtin_amdgcn_mfma_f32_32x32x16_f16(av, bb.h, accO, 0, 0, 0);
                unsigned int ne = sW[it + 17 + j];
                eq[j + 1] = ne;
                bq[j + 1] = bpack[(size_t)(ne & 4095u) * 64 + lane];
            }
        }
    }

    // growth + sum over q (lanes l, l^8, l^16) -> Uc (f16)
    const int q = (lane & 31) >> 3, sy = lane & 7;
    const float mq = mp[c + 3 * q];
    const float sq = sp[c + 3 * q];
    const float hq = hp[c + 3 * q];
    const float i2s = 1.f / (2.f * sq * sq);
    #pragma unroll
    for (int r = 0; r < 16; ++r) {
        float d = (accE[r] + accO[r]) - mq;
        float gg = (2.f * expf(-d * d * i2s) - 1.f) * hq;
        gg += __shfl_xor(gg, 8);
        gg += __shfl_xor(gg, 16);
        if ((lane & 24) == 0) {
            int row = (r & 3) + ((r >> 2) << 3) + (g << 2);
            Uc[((size_t)(b << 16) + ((x0 + row) << 8) + (y0 + 8 * wid + sy)) * 3 + c] = (f16)gg;
        }
    }
}

// ------- kernel 6: fused sobel+flow+mus + RT, PER-CHANNEL blocks (grid 64x12) -------
#define FTW 44
#define FSW 45
#define PLH (FSW * FTW)           // 1980 elems per plane
__global__ __launch_bounds__(256) void lenia_flowrt(
        const f16* __restrict__ Atr, const f16* __restrict__ Uc,
        float* __restrict__ out) {
    extern __shared__ char fraw[];
    f16*    ucp = (f16*)fraw;                    // [PLH]       uc, this channel
    f16*    atp = (f16*)(fraw + PLH * 2);        // [3][PLH]    A, all channels
    float2* muq = (float2*)(fraw + 8 * PLH);     // [PLH]       (dx, dy), this channel

    int bc = blockIdx.y;                         // 12: b*3+c
    int b = bc / 3, c = bc - b * 3;
    int t = blockIdx.x;                          // 64 tiles of 32x32
    int x0 = (t >> 3) << 5, y0 = (t & 7) << 5;
    const f16* A0 = Atr + (size_t)(b * 3) * 65536;
    const f16* Ub = Uc + ((size_t)b << 16) * 3;

    for (int idx = threadIdx.x; idx < FTW * FTW; idx += 256) {
        int si = idx / FTW, sj = idx - si * FTW;
        int gi = (x0 - 6 + si) & 255, gj = (y0 - 6 + sj) & 255;
        int pix = (gi << 8) + gj;
        int o = si * FSW + sj;
        ucp[o] = Ub[(size_t)pix * 3 + c];
        atp[o] = A0[pix];
        atp[PLH + o] = A0[65536 + pix];
        atp[2 * PLH + o] = A0[131072 + pix];
    }
    __syncthreads();

    // mus phase: 42x42 cells (this channel only)
    for (int idx = threadIdx.x; idx < 42 * 42; idx += 256) {
        int ci = idx / 42, cj = idx - ci * 42;
        int si = ci + 1, sj = cj + 1;
        int o = si * FSW + sj;
        int vx = x0 - 6 + si, vy = y0 - 6 + sj;
        float sx = (vx < 0 || vx > 255) ? 1e7f : 0.f;
        float syv = (vy < 0 || vy > 255) ? 1e7f : 0.f;

        float as[3][3];
        #pragma unroll
        for (int i = 0; i < 3; ++i)
            #pragma unroll
            for (int j = 0; j < 3; ++j) {
                int oo = o + (i - 1) * FSW + (j - 1);
                as[i][j] = (float)atp[oo] + (float)atp[PLH + oo] + (float)atp[2 * PLH + oo];
            }
        float gxA = ((as[2][0] + 2.f * as[2][1] + as[2][2])
                   - (as[0][0] + 2.f * as[0][1] + as[0][2])) * 0.125f;
        float gyA = ((as[0][2] + 2.f * as[1][2] + as[2][2])
                   - (as[0][0] + 2.f * as[1][0] + as[2][0])) * 0.125f;

        float u00 = ucp[o - FSW - 1], u01 = ucp[o - FSW], u02 = ucp[o - FSW + 1];
        float u10 = ucp[o - 1],                          u12 = ucp[o + 1];
        float u20 = ucp[o + FSW - 1], u21 = ucp[o + FSW], u22 = ucp[o + FSW + 1];
        float gx = ((u20 + 2.f * u21 + u22) - (u00 + 2.f * u01 + u02)) * 0.125f;
        float gy = ((u02 + 2.f * u12 + u22) - (u00 + 2.f * u10 + u20)) * 0.125f;
        float a = (float)atp[c * PLH + o];
        float alpha = fminf(a * a, 1.f);
        float Fx = gx * (1.f - alpha) - gxA * alpha;
        float Fy = gy * (1.f - alpha) - gyA * alpha;
        float dx = fminf(fmaxf(0.2f * Fx, -4.35f), 4.35f) + sx;
        float dy = fminf(fmaxf(0.2f * Fy, -4.35f), 4.35f) + syv;
        muq[o] = make_float2(dx, dy);
    }
    __syncthreads();

    // gather: thread = (x col tx, y quad tyg), this channel
    int tx = threadIdx.x & 31, tyg = threadIdx.x >> 5;
    int ty0 = tyg << 2;
    float a0 = 0.f, a1 = 0.f, a2 = 0.f, a3 = 0.f;
    const f16* ac = atp + c * PLH;

    for (int dxs = 0; dxs < 11; ++dxs) {
        float fdx = (float)(5 - dxs);
        int rowb = (tx + 1 + dxs) * FSW + (ty0 + 1);
        #pragma unroll
        for (int sjj = 0; sjj < 14; ++sjj) {
            float fdy = (float)(5 - sjj);
            float2 mu = muq[rowb + sjj];
            float av = (float)ac[rowb + sjj];
            float wx = fminf(fmaxf(1.15f - fabsf(fdx - mu.x), 0.f), 1.f);
            float awx = av * wx;
            float e0 = fdy - mu.y;
            a0 = fmaf(awx, fminf(fmaxf(1.15f - fabsf(e0), 0.f), 1.f), a0);
            a1 = fmaf(awx, fminf(fmaxf(1.15f - fabsf(e0 + 1.f), 0.f), 1.f), a1);
            a2 = fmaf(awx, fminf(fmaxf(1.15f - fabsf(e0 + 2.f), 0.f), 1.f), a2);
            a3 = fmaf(awx, fminf(fmaxf(1.15f - fabsf(e0 + 3.f), 0.f), 1.f), a3);
        }
    }
    const float inv = 1.0f / 1.69f;   // 1/(4*sigma^2)
    size_t ob = ((size_t)(b << 16) + ((x0 + tx) << 8) + (y0 + ty0)) * 3 + c;
    out[ob]     = a0 * inv;
    out[ob + 3] = a1 * inv;
    out[ob + 6] = a2 * inv;
    out[ob + 9] = a3 * inv;
}

extern "C" void kernel_launch(void* const* d_in, const int* in_sizes, int n_in,
                              void* d_out, int out_size, void* d_ws, size_t ws_size,
                              hipStream_t stream) {
    const float* A  = (const float*)d_in[0];
    const float* Kn = (const float*)d_in[1];
    const float* m  = (const float*)d_in[2];
    const float* s  = (const float*)d_in[3];
    const float* h  = (const float*)d_in[4];

    char* ws = (char*)d_ws;
    int*          radii = (int*)ws;                        // 16 B
    int*          nschd = (int*)(ws + 16);
    int*          rowr  = (int*)(ws + 64);                 // 267*4
    int2*         meta  = (int2*)(ws + 2048);              // 267*8
    int2*         meta2 = (int2*)(ws + 8192);              // 267*8
    unsigned int* sched = (unsigned int*)(ws + 16384);     // 12 KB
    f16*          Ktr   = (f16*)(ws + 32768);              // 1.57 MB (dead after bpack)
    f16*          Atr   = (f16*)(ws + 1605632);            // 1.57 MB
    uint4*        bpack = (uint4*)(ws + 3178496);          // 2.19 MB -> ends 5.37 MB
    f16*          Uc    = (f16*)(ws + 32768);              // 1.57 MB, OVERLAYS dead Ktr

    lenia_meta<<<3 * NROWS, 128, 0, stream>>>(Kn, meta, rowr);
    lenia_sched<<<3, 128, 0, stream>>>(meta, rowr, meta2, sched, nschd, radii);
    lenia_trans<<<1280, 256, 0, stream>>>(Kn, A, Ktr, Atr);
    lenia_bpack<<<(NFRAG + 4) / 4, 256, 0, stream>>>(Ktr, meta2, bpack);
    lenia_conv<<<dim3(64, 12), 256, TROWS * ST * sizeof(f16), stream>>>(
        Atr, bpack, sched, nschd, radii, m, s, h, Uc);
    lenia_flowrt<<<dim3(64, 12), 256, 8 * PLH + PLH * 8, stream>>>(
        Atr, Uc, (float*)d_out);
}

// Round 13
// 74.671 us; speedup vs baseline: 1.2051x; 1.0037x over previous
//
#include <hip/hip_runtime.h>

// FlowLenia single step — MFMA implicit-GEMM convolution (f16), fused flow+RT.
// A:[4,1,256,256,3] f32, Kn:[256,256,12] f32, m/s/h:[12], c0/c1 = arange(12)%3.
// out nA:[4,1,256,256,3] f32.
//
// Conv = r12 structure (256 thr, 4 waves one y-octet each, dual acc chains,
// 16-deep in-place B ring) + SCALAR (readfirstlane) schedule addressing.
// Pipeline: 5 launches — meta, sched, prep2 (bpack-from-Kn + A-transpose
// fused), conv, flowrt. Ktr eliminated.

typedef _Float16 f16;
typedef __attribute__((ext_vector_type(8))) _Float16 half8;
typedef __attribute__((ext_vector_type(16))) float f32x16;

#define RMAX 44
#define NROWS 89                  // 2*RMAX+1
#define NDMAX 8
#define NFRAG (3*NROWS*NDMAX)     // real fragments; slot NFRAG = zeros
#define NBPK ((NFRAG + 4) / 4)    // bpack blocks (4 frags / 256-thr block)
#define ST 168                    // LDS row stride (f16), 21 half8 chunks
#define TROWS 120                 // 32 + 2*RMAX
#define SCHED_STRIDE 1024
#define KTHR 1e-7f

// ---------------- kernel 1: per-(c,di) dj bounds + per-row radius ----------------
__global__ __launch_bounds__(128) void lenia_meta(const float* __restrict__ Kn,
                                                  int2* __restrict__ meta,
                                                  int* __restrict__ rowr) {
    int blk = blockIdx.x;                 // 3*NROWS
    int c = blk / NROWS, ri = blk - c * NROWS;
    int di = ri - RMAX;
    int t = threadIdx.x;
    int dj = t - RMAX;
    int act = 0;
    if (t < NROWS) {
        size_t base = (size_t)(((di + 128) << 8) | (dj + 128)) * 12 + c;
        float k0 = Kn[base], k1 = Kn[base + 3], k2 = Kn[base + 6], k3 = Kn[base + 9];
        act = (fmaxf(fmaxf(k0, k1), fmaxf(k2, k3)) > KTHR) ? 1 : 0;
    }
    __shared__ int smn[128], smx[128];
    smn[t] = act ? dj : 1000;
    smx[t] = act ? dj : -1000;
    __syncthreads();
    for (int s = 64; s > 0; s >>= 1) {
        if (t < s) { smn[t] = min(smn[t], smn[t + s]); smx[t] = max(smx[t], smx[t + s]); }
        __syncthreads();
    }
    if (t == 0) {
        int jmn = smn[0], jmx = smx[0];
        if (jmx < jmn) { meta[blk] = make_int2(1, 0); rowr[blk] = 0; }
        else {
            meta[blk] = make_int2(jmn, jmx);
            rowr[blk] = max(abs(di), max(abs(jmn), abs(jmx)));
        }
    }
}

// ------------- kernel 2: chunk geometry + flat schedule (w/ LDS offsets) + radii -------------
__global__ __launch_bounds__(128) void lenia_sched(const int2* __restrict__ meta,
                                                   const int* __restrict__ rowr,
                                                   int2* __restrict__ meta2,
                                                   unsigned int* __restrict__ sched,
                                                   int* __restrict__ nsched,
                                                   int* __restrict__ radii) {
    int c = blockIdx.x;                   // 3 blocks
    int t = threadIdx.x;
    __shared__ int pre[NROWS], nds[NROWS], rmx[128];
    int nd = 0, d0 = 0;
    if (t < NROWS) {
        int2 bm = meta[c * NROWS + t];
        if (bm.y >= bm.x) {
            d0 = ((bm.x - 7) >> 3) << 3;          // delta0 <= jmn-7, mult of 8
            nd = ((bm.y + 7 - d0) >> 4) + 1;      // cover dj' = jmx for sy up to 7
        }
        meta2[c * NROWS + t] = make_int2(d0, nd);
        nds[t] = nd;
    }
    rmx[t] = (t < NROWS) ? rowr[c * NROWS + t] : 0;
    __syncthreads();
    for (int s = 64; s > 0; s >>= 1) {
        if (t < s) rmx[t] = max(rmx[t], rmx[t + s]);
        __syncthreads();
    }
    __shared__ int tot;
    if (t == 0) {
        radii[c] = rmx[0];
        int acc = 0;
        for (int i = 0; i < NROWS; ++i) { pre[i] = acc; acc += nds[i]; }
        tot = acc;
    }
    __syncthreads();
    if (t < NROWS && nd > 0) {
        int base = pre[t];
        for (int i = 0; i < nd; ++i) {
            int delta = d0 + 16 * i;
            unsigned int off = (unsigned int)(t * ST + delta + 128);   // 14 bits
            sched[c * SCHED_STRIDE + base + i] =
                (unsigned int)((c * NROWS + t) * NDMAX + i) | (off << 12);
        }
    }
    if (t == 0) {
        int ns = (tot + 7) & ~7;
        unsigned int padoff = (unsigned int)(RMAX * ST + 128);
        for (int i = tot; i < ns + 48; ++i)       // pads: zero frag, valid lds addr
            sched[c * SCHED_STRIDE + i] = (unsigned int)NFRAG | (padoff << 12);
        nsched[c] = ns;
    }
}

// ------- kernel 3: FUSED bpack-from-Kn (blocks < NBPK) + A-transpose (rest) -------
__global__ __launch_bounds__(256) void lenia_prep2(const float* __restrict__ Kn,
                                                   const float* __restrict__ A,
                                                   const int2* __restrict__ meta2,
                                                   uint4* __restrict__ bpack,
                                                   f16* __restrict__ Atr) {
    int blk = blockIdx.x;
    if (blk < NBPK) {                     // ---- bpack part ----
        int fi = blk * 4 + (threadIdx.x >> 6);
        int l = threadIdx.x & 63;
        if (fi > NFRAG) return;
        union { f16 h[8]; uint4 u; } pk;
        if (fi == NFRAG) {
            pk.u = make_uint4(0, 0, 0, 0);
            bpack[(size_t)fi * 64 + l] = pk.u;
            return;
        }
        int c = fi / (NROWS * NDMAX);
        int rem = fi - c * (NROWS * NDMAX);
        int ri = rem >> 3, didx = rem & 7;
        int di = ri - RMAX;
        int delta = meta2[c * NROWS + ri].x + 16 * didx;
        int q = (l & 31) >> 3, sy = l & 7, g = l >> 5;
        int dj0 = delta + 8 * g - sy;     // in [-63, 71]: row-local, in-bounds
        const float* src = Kn + (size_t)(((di + 128) << 8) + (dj0 + 128)) * 12 + c + 3 * q;
        #pragma unroll
        for (int j = 0; j < 8; ++j) pk.h[j] = (f16)src[j * 12];
        bpack[(size_t)fi * 64 + l] = pk.u;
    } else {                              // ---- A-transpose part ----
        int px = (blk - NBPK) * 256 + threadIdx.x;   // 0..262143
        int b = px >> 16, rem = px & 65535;
        const float* ap = A + (size_t)px * 3;
        Atr[(size_t)(b * 3 + 0) * 65536 + rem] = (f16)ap[0];
        Atr[(size_t)(b * 3 + 1) * 65536 + rem] = (f16)ap[1];
        Atr[(size_t)(b * 3 + 2) * 65536 + rem] = (f16)ap[2];
    }
}

// ---------------- kernel 4: MFMA conv + growth -> Uc (f16, in ws) ----------------
// r12 structure; 16-deep in-place B ring; SCALAR schedule addressing.
__global__ __launch_bounds__(256) void lenia_conv(
        const f16* __restrict__ Atr, const uint4* __restrict__ bpack,
        const unsigned int* __restrict__ sched, const int* __restrict__ nsched,
        const int* __restrict__ radii,
        const float* __restrict__ mp, const float* __restrict__ sp,
        const float* __restrict__ hp, f16* __restrict__ Uc) {
    extern __shared__ f16 smh[];

    const int tid = threadIdx.x;
    const int bc = blockIdx.y;
    const int b = bc / 3, c = bc - b * 3;
    const int x0 = (blockIdx.x >> 3) << 5;
    const int y0 = (blockIdx.x & 7) << 5;

    const int R = __builtin_amdgcn_readfirstlane(min(max(radii[c], 1), RMAX));
    const int R8 = (R + 7) & ~7;
    const int colbase = y0 - R8 - 16;     // mult of 8
    const int rows = 32 + 2 * R;
    const f16* Ap = Atr + (size_t)(b * 3 + c) * 65536;

    {   // staging: half8 (16B) chunks; 21 chunks/row
        int nchunk = rows * 21;
        int tr = tid / 21, rem = tid - tr * 21;
        for (int ci = tid; ci < nchunk; ci += 256) {
            int gi = (x0 - R + tr) & 255;
            int gj = (colbase + rem * 8) & 255;   // mult of 8 -> never crosses wrap
            *(half8*)(smh + tr * ST + rem * 8) = *(const half8*)(Ap + (gi << 8) + gj);
            tr += 12; rem += 4;                   // +256 chunks = 12*21 + 4
            if (rem >= 21) { rem -= 21; ++tr; }
        }
    }
    __syncthreads();

    const int lane = tid & 63, wid = tid >> 6;    // wid 0..3, octet per wave
    const int m = lane & 31, g = lane >> 5;
    const int abase = (m + R - RMAX) * ST + 8 * wid + R8 + 16 + 8 * g - 128;

    const unsigned int* sW = sched + c * SCHED_STRIDE;
    const int ns = __builtin_amdgcn_readfirstlane(nsched[c]);

    f32x16 accE, accO;
    #pragma unroll
    for (int r = 0; r < 16; ++r) { accE[r] = 0.f; accO[r] = 0.f; }

    // schedule is wave-uniform: keep it in SGPRs (scalar addressing for B)
    int eq[16];
    uint4 bq[16];
    #pragma unroll
    for (int j = 0; j < 16; ++j) {
        int e = __builtin_amdgcn_readfirstlane((int)sW[j]);
        eq[j] = e;
        bq[j] = bpack[(size_t)(e & 4095) * 64 + lane];
    }

    for (int it = 0; it < ns; it += 16) {
        #pragma unroll
        for (int j = 0; j < 16; j += 2) {
            {   // even entry -> accE
                half8 av = *(const half8*)(smh + abase + (eq[j] >> 12));
                union { uint4 u; half8 h; } bb; bb.u = bq[j];
                accE = __builtin_amdgcn_mfma_f32_32x32x16_f16(av, bb.h, accE, 0, 0, 0);
                int ne = __builtin_amdgcn_readfirstlane((int)sW[it + 16 + j]);
                eq[j] = ne;
                bq[j] = bpack[(size_t)(ne & 4095) * 64 + lane];
            }
            {   // odd entry -> accO (independent chain)
                half8 av = *(const half8*)(smh + abase + (eq[j + 1] >> 12));
                union { uint4 u; half8 h; } bb; bb.u = bq[j + 1];
                accO = __builtin_amdgcn_mfma_f32_32x32x16_f16(av, bb.h, accO, 0, 0, 0);
                int ne = __builtin_amdgcn_readfirstlane((int)sW[it + 17 + j]);
                eq[j + 1] = ne;
                bq[j + 1] = bpack[(size_t)(ne & 4095) * 64 + lane];
            }
        }
    }

    // growth + sum over q (lanes l, l^8, l^16) -> Uc (f16)
    const int q = (lane & 31) >> 3, sy = lane & 7;
    const float mq = mp[c + 3 * q];
    const float sq = sp[c + 3 * q];
    const float hq = hp[c + 3 * q];
    const float i2s = 1.f / (2.f * sq * sq);
    #pragma unroll
    for (int r = 0; r < 16; ++r) {
        float d = (accE[r] + accO[r]) - mq;
        float gg = (2.f * expf(-d * d * i2s) - 1.f) * hq;
        gg += __shfl_xor(gg, 8);
        gg += __shfl_xor(gg, 16);
        if ((lane & 24) == 0) {
            int row = (r & 3) + ((r >> 2) << 3) + (g << 2);
            Uc[((size_t)(b << 16) + ((x0 + row) << 8) + (y0 + 8 * wid + sy)) * 3 + c] = (f16)gg;
        }
    }
}

// ------- kernel 5: fused sobel+flow+mus + RT, PER-CHANNEL blocks (grid 64x12) -------
#define FTW 44
#define FSW 45
#define PLH (FSW * FTW)           // 1980 elems per plane
__global__ __launch_bounds__(256) void lenia_flowrt(
        const f16* __restrict__ Atr, const f16* __restrict__ Uc,
        float* __restrict__ out) {
    extern __shared__ char fraw[];
    f16*    ucp = (f16*)fraw;                    // [PLH]       uc, this channel
    f16*    atp = (f16*)(fraw + PLH * 2);        // [3][PLH]    A, all channels
    float2* muq = (float2*)(fraw + 8 * PLH);     // [PLH]       (dx, dy), this channel

    int bc = blockIdx.y;                         // 12: b*3+c
    int b = bc / 3, c = bc - b * 3;
    int t = blockIdx.x;                          // 64 tiles of 32x32
    int x0 = (t >> 3) << 5, y0 = (t & 7) << 5;
    const f16* A0 = Atr + (size_t)(b * 3) * 65536;
    const f16* Ub = Uc + ((size_t)b << 16) * 3;

    for (int idx = threadIdx.x; idx < FTW * FTW; idx += 256) {
        int si = idx / FTW, sj = idx - si * FTW;
        int gi = (x0 - 6 + si) & 255, gj = (y0 - 6 + sj) & 255;
        int pix = (gi << 8) + gj;
        int o = si * FSW + sj;
        ucp[o] = Ub[(size_t)pix * 3 + c];
        atp[o] = A0[pix];
        atp[PLH + o] = A0[65536 + pix];
        atp[2 * PLH + o] = A0[131072 + pix];
    }
    __syncthreads();

    // mus phase: 42x42 cells (this channel only)
    for (int idx = threadIdx.x; idx < 42 * 42; idx += 256) {
        int ci = idx / 42, cj = idx - ci * 42;
        int si = ci + 1, sj = cj + 1;
        int o = si * FSW + sj;
        int vx = x0 - 6 + si, vy = y0 - 6 + sj;
        float sx = (vx < 0 || vx > 255) ? 1e7f : 0.f;
        float syv = (vy < 0 || vy > 255) ? 1e7f : 0.f;

        float as[3][3];
        #pragma unroll
        for (int i = 0; i < 3; ++i)
            #pragma unroll
            for (int j = 0; j < 3; ++j) {
                int oo = o + (i - 1) * FSW + (j - 1);
                as[i][j] = (float)atp[oo] + (float)atp[PLH + oo] + (float)atp[2 * PLH + oo];
            }
        float gxA = ((as[2][0] + 2.f * as[2][1] + as[2][2])
                   - (as[0][0] + 2.f * as[0][1] + as[0][2])) * 0.125f;
        float gyA = ((as[0][2] + 2.f * as[1][2] + as[2][2])
                   - (as[0][0] + 2.f * as[1][0] + as[2][0])) * 0.125f;

        float u00 = ucp[o - FSW - 1], u01 = ucp[o - FSW], u02 = ucp[o - FSW + 1];
        float u10 = ucp[o - 1],                          u12 = ucp[o + 1];
        float u20 = ucp[o + FSW - 1], u21 = ucp[o + FSW], u22 = ucp[o + FSW + 1];
        float gx = ((u20 + 2.f * u21 + u22) - (u00 + 2.f * u01 + u02)) * 0.125f;
        float gy = ((u02 + 2.f * u12 + u22) - (u00 + 2.f * u10 + u20)) * 0.125f;
        float a = (float)atp[c * PLH + o];
        float alpha = fminf(a * a, 1.f);
        float Fx = gx * (1.f - alpha) - gxA * alpha;
        float Fy = gy * (1.f - alpha) - gyA * alpha;
        float dx = fminf(fmaxf(0.2f * Fx, -4.35f), 4.35f) + sx;
        float dy = fminf(fmaxf(0.2f * Fy, -4.35f), 4.35f) + syv;
        muq[o] = make_float2(dx, dy);
    }
    __syncthreads();

    // gather: thread = (x col tx, y quad tyg), this channel
    int tx = threadIdx.x & 31, tyg = threadIdx.x >> 5;
    int ty0 = tyg << 2;
    float a0 = 0.f, a1 = 0.f, a2 = 0.f, a3 = 0.f;
    const f16* ac = atp + c * PLH;

    for (int dxs = 0; dxs < 11; ++dxs) {
        float fdx = (float)(5 - dxs);
        int rowb = (tx + 1 + dxs) * FSW + (ty0 + 1);
        #pragma unroll
        for (int sjj = 0; sjj < 14; ++sjj) {
            float fdy = (float)(5 - sjj);
            float2 mu = muq[rowb + sjj];
            float av = (float)ac[rowb + sjj];
            float wx = fminf(fmaxf(1.15f - fabsf(fdx - mu.x), 0.f), 1.f);
            float awx = av * wx;
            float e0 = fdy - mu.y;
            a0 = fmaf(awx, fminf(fmaxf(1.15f - fabsf(e0), 0.f), 1.f), a0);
            a1 = fmaf(awx, fminf(fmaxf(1.15f - fabsf(e0 + 1.f), 0.f), 1.f), a1);
            a2 = fmaf(awx, fminf(fmaxf(1.15f - fabsf(e0 + 2.f), 0.f), 1.f), a2);
            a3 = fmaf(awx, fminf(fmaxf(1.15f - fabsf(e0 + 3.f), 0.f), 1.f), a3);
        }
    }
    const float inv = 1.0f / 1.69f;   // 1/(4*sigma^2)
    size_t ob = ((size_t)(b << 16) + ((x0 + tx) << 8) + (y0 + ty0)) * 3 + c;
    out[ob]     = a0 * inv;
    out[ob + 3] = a1 * inv;
    out[ob + 6] = a2 * inv;
    out[ob + 9] = a3 * inv;
}

extern "C" void kernel_launch(void* const* d_in, const int* in_sizes, int n_in,
                              void* d_out, int out_size, void* d_ws, size_t ws_size,
                              hipStream_t stream) {
    const float* A  = (const float*)d_in[0];
    const float* Kn = (const float*)d_in[1];
    const float* m  = (const float*)d_in[2];
    const float* s  = (const float*)d_in[3];
    const float* h  = (const float*)d_in[4];

    char* ws = (char*)d_ws;
    int*          radii = (int*)ws;                        // 16 B
    int*          nschd = (int*)(ws + 16);
    int*          rowr  = (int*)(ws + 64);                 // 267*4
    int2*         meta  = (int2*)(ws + 2048);              // 267*8
    int2*         meta2 = (int2*)(ws + 8192);              // 267*8
    unsigned int* sched = (unsigned int*)(ws + 16384);     // 12 KB
    f16*          Atr   = (f16*)(ws + 32768);              // 1.57 MB
    uint4*        bpack = (uint4*)(ws + 1605632);          // 2.19 MB
    f16*          Uc    = (f16*)(ws + 3793920);            // 1.57 MB -> ends 5.37 MB

    lenia_meta<<<3 * NROWS, 128, 0, stream>>>(Kn, meta, rowr);
    lenia_sched<<<3, 128, 0, stream>>>(meta, rowr, meta2, sched, nschd, radii);
    lenia_prep2<<<NBPK + 1024, 256, 0, stream>>>(Kn, A, meta2, bpack, Atr);
    lenia_conv<<<dim3(64, 12), 256, TROWS * ST * sizeof(f16), stream>>>(
        Atr, bpack, sched, nschd, radii, m, s, h, Uc);
    lenia_flowrt<<<dim3(64, 12), 256, 8 * PLH + PLH * 8, stream>>>(
        Atr, Uc, (float*)d_out);
}

// Round 14
// 74.399 us; speedup vs baseline: 1.2095x; 1.0036x over previous
//
#include <hip/hip_runtime.h>

// FlowLenia single step — MFMA implicit-GEMM convolution (f16), fused flow+RT.
// A:[4,1,256,256,3] f32, Kn:[256,256,12] f32, m/s/h:[12], c0/c1 = arange(12)%3.
// out nA:[4,1,256,256,3] f32.
//
// Conv: 256 thr = 4 waves = 2 schedule-halves x 2 octet-pairs. Wave (h,p) runs
// half h of the schedule for octets {2p,2p+1}: 1 B-load -> 2 MFMAs (B traffic
// halved vs r13; dual acc chains come free from the octet pair). 8-deep
// in-place B ring, scalar (readfirstlane) schedule. Cross-half LDS reduction.

typedef _Float16 f16;
typedef __attribute__((ext_vector_type(8))) _Float16 half8;
typedef __attribute__((ext_vector_type(16))) float f32x16;

#define RMAX 44
#define NROWS 89                  // 2*RMAX+1
#define NDMAX 8
#define NFRAG (3*NROWS*NDMAX)     // real fragments; slot NFRAG = zeros
#define NBPK ((NFRAG + 4) / 4)    // bpack blocks (4 frags / 256-thr block)
#define ST 168                    // LDS row stride (f16), 21 half8 chunks
#define TROWS 120                 // 32 + 2*RMAX
#define SCHED_STRIDE 1024
#define KTHR 1e-7f

// ---------------- kernel 1: per-(c,di) dj bounds + per-row radius ----------------
__global__ __launch_bounds__(128) void lenia_meta(const float* __restrict__ Kn,
                                                  int2* __restrict__ meta,
                                                  int* __restrict__ rowr) {
    int blk = blockIdx.x;                 // 3*NROWS
    int c = blk / NROWS, ri = blk - c * NROWS;
    int di = ri - RMAX;
    int t = threadIdx.x;
    int dj = t - RMAX;
    int act = 0;
    if (t < NROWS) {
        size_t base = (size_t)(((di + 128) << 8) | (dj + 128)) * 12 + c;
        float k0 = Kn[base], k1 = Kn[base + 3], k2 = Kn[base + 6], k3 = Kn[base + 9];
        act = (fmaxf(fmaxf(k0, k1), fmaxf(k2, k3)) > KTHR) ? 1 : 0;
    }
    __shared__ int smn[128], smx[128];
    smn[t] = act ? dj : 1000;
    smx[t] = act ? dj : -1000;
    __syncthreads();
    for (int s = 64; s > 0; s >>= 1) {
        if (t < s) { smn[t] = min(smn[t], smn[t + s]); smx[t] = max(smx[t], smx[t + s]); }
        __syncthreads();
    }
    if (t == 0) {
        int jmn = smn[0], jmx = smx[0];
        if (jmx < jmn) { meta[blk] = make_int2(1, 0); rowr[blk] = 0; }
        else {
            meta[blk] = make_int2(jmn, jmx);
            rowr[blk] = max(abs(di), max(abs(jmn), abs(jmx)));
        }
    }
}

// ------------- kernel 2: chunk geometry + flat schedule (w/ LDS offsets) + radii -------------
__global__ __launch_bounds__(128) void lenia_sched(const int2* __restrict__ meta,
                                                   const int* __restrict__ rowr,
                                                   int2* __restrict__ meta2,
                                                   unsigned int* __restrict__ sched,
                                                   int* __restrict__ nsched,
                                                   int* __restrict__ radii) {
    int c = blockIdx.x;                   // 3 blocks
    int t = threadIdx.x;
    __shared__ int pre[NROWS], nds[NROWS], rmx[128];
    int nd = 0, d0 = 0;
    if (t < NROWS) {
        int2 bm = meta[c * NROWS + t];
        if (bm.y >= bm.x) {
            d0 = ((bm.x - 7) >> 3) << 3;          // delta0 <= jmn-7, mult of 8
            nd = ((bm.y + 7 - d0) >> 4) + 1;      // cover dj' = jmx for sy up to 7
        }
        meta2[c * NROWS + t] = make_int2(d0, nd);
        nds[t] = nd;
    }
    rmx[t] = (t < NROWS) ? rowr[c * NROWS + t] : 0;
    __syncthreads();
    for (int s = 64; s > 0; s >>= 1) {
        if (t < s) rmx[t] = max(rmx[t], rmx[t + s]);
        __syncthreads();
    }
    __shared__ int tot;
    if (t == 0) {
        radii[c] = rmx[0];
        int acc = 0;
        for (int i = 0; i < NROWS; ++i) { pre[i] = acc; acc += nds[i]; }
        tot = acc;
    }
    __syncthreads();
    if (t < NROWS && nd > 0) {
        int base = pre[t];
        for (int i = 0; i < nd; ++i) {
            int delta = d0 + 16 * i;
            unsigned int off = (unsigned int)(t * ST + delta + 128);   // 14 bits
            sched[c * SCHED_STRIDE + base + i] =
                (unsigned int)((c * NROWS + t) * NDMAX + i) | (off << 12);
        }
    }
    if (t == 0) {
        int ns = (tot + 15) & ~15;        // mult of 16 -> halves are mult of 8
        unsigned int padoff = (unsigned int)(RMAX * ST + 128);
        for (int i = tot; i < ns + 48; ++i)       // pads: zero frag, valid lds addr
            sched[c * SCHED_STRIDE + i] = (unsigned int)NFRAG | (padoff << 12);
        nsched[c] = ns;
    }
}

// ------- kernel 3: FUSED bpack-from-Kn (blocks < NBPK) + A-transpose (rest) -------
__global__ __launch_bounds__(256) void lenia_prep2(const float* __restrict__ Kn,
                                                   const float* __restrict__ A,
                                                   const int2* __restrict__ meta2,
                                                   uint4* __restrict__ bpack,
                                                   f16* __restrict__ Atr) {
    int blk = blockIdx.x;
    if (blk < NBPK) {                     // ---- bpack part ----
        int fi = blk * 4 + (threadIdx.x >> 6);
        int l = threadIdx.x & 63;
        if (fi > NFRAG) return;
        union { f16 h[8]; uint4 u; } pk;
        if (fi == NFRAG) {
            pk.u = make_uint4(0, 0, 0, 0);
            bpack[(size_t)fi * 64 + l] = pk.u;
            return;
        }
        int c = fi / (NROWS * NDMAX);
        int rem = fi - c * (NROWS * NDMAX);
        int ri = rem >> 3, didx = rem & 7;
        int di = ri - RMAX;
        int delta = meta2[c * NROWS + ri].x + 16 * didx;
        int q = (l & 31) >> 3, sy = l & 7, g = l >> 5;
        int dj0 = delta + 8 * g - sy;     // in [-63, 71]: row-local, in-bounds
        const float* src = Kn + (size_t)(((di + 128) << 8) + (dj0 + 128)) * 12 + c + 3 * q;
        #pragma unroll
        for (int j = 0; j < 8; ++j) pk.h[j] = (f16)src[j * 12];
        bpack[(size_t)fi * 64 + l] = pk.u;
    } else {                              // ---- A-transpose part ----
        int px = (blk - NBPK) * 256 + threadIdx.x;   // 0..262143
        int b = px >> 16, rem = px & 65535;
        const float* ap = A + (size_t)px * 3;
        Atr[(size_t)(b * 3 + 0) * 65536 + rem] = (f16)ap[0];
        Atr[(size_t)(b * 3 + 1) * 65536 + rem] = (f16)ap[1];
        Atr[(size_t)(b * 3 + 2) * 65536 + rem] = (f16)ap[2];
    }
}

// ---------------- kernel 4: MFMA conv + growth -> Uc (f16, in ws) ----------------
// Wave (h = wid&1, p = wid>>1): schedule half h, octets {2p, 2p+1}.
// Per entry: 1 B-load, 2 A ds_reads, 2 MFMAs. Cross-half LDS reduce, growth on h=0.
__global__ __launch_bounds__(256) void lenia_conv(
        const f16* __restrict__ Atr, const uint4* __restrict__ bpack,
        const unsigned int* __restrict__ sched, const int* __restrict__ nsched,
        const int* __restrict__ radii,
        const float* __restrict__ mp, const float* __restrict__ sp,
        const float* __restrict__ hp, f16* __restrict__ Uc) {
    extern __shared__ f16 smh[];

    const int tid = threadIdx.x;
    const int bc = blockIdx.y;
    const int b = bc / 3, c = bc - b * 3;
    const int x0 = (blockIdx.x >> 3) << 5;
    const int y0 = (blockIdx.x & 7) << 5;

    const int R = __builtin_amdgcn_readfirstlane(min(max(radii[c], 1), RMAX));
    const int R8 = (R + 7) & ~7;
    const int colbase = y0 - R8 - 16;     // mult of 8
    const int rows = 32 + 2 * R;
    const f16* Ap = Atr + (size_t)(b * 3 + c) * 65536;

    {   // staging: half8 (16B) chunks; 21 chunks/row
        int nchunk = rows * 21;
        int tr = tid / 21, rem = tid - tr * 21;
        for (int ci = tid; ci < nchunk; ci += 256) {
            int gi = (x0 - R + tr) & 255;
            int gj = (colbase + rem * 8) & 255;   // mult of 8 -> never crosses wrap
            *(half8*)(smh + tr * ST + rem * 8) = *(const half8*)(Ap + (gi << 8) + gj);
            tr += 12; rem += 4;                   // +256 chunks = 12*21 + 4
            if (rem >= 21) { rem -= 21; ++tr; }
        }
    }
    __syncthreads();

    const int lane = tid & 63, wid = tid >> 6;
    const int h = wid & 1, p = wid >> 1;          // half h, octet-pair p
    const int m = lane & 31, g = lane >> 5;
    // octet 2p base (octet 2p+1 = +8), incl. the -128 bias of sched offsets
    const int abase = (m + R - RMAX) * ST + 16 * p + R8 + 16 + 8 * g - 128;

    const int ns = __builtin_amdgcn_readfirstlane(nsched[c]);   // mult of 16
    const int nsH = ns >> 1;                                    // mult of 8
    const unsigned int* sW = sched + c * SCHED_STRIDE + h * nsH;

    f32x16 accA, accB;                    // octet 2p / octet 2p+1 chains
    #pragma unroll
    for (int r = 0; r < 16; ++r) { accA[r] = 0.f; accB[r] = 0.f; }

    int eq[8];
    uint4 bq[8];
    #pragma unroll
    for (int j = 0; j < 8; ++j) {
        int e = __builtin_amdgcn_readfirstlane((int)sW[j]);
        eq[j] = e;
        bq[j] = bpack[(size_t)(e & 4095) * 64 + lane];
    }

    for (int it = 0; it < nsH; it += 8) {
        #pragma unroll
        for (int j = 0; j < 8; ++j) {
            const int off = abase + (eq[j] >> 12);
            half8 a0 = *(const half8*)(smh + off);
            half8 a1 = *(const half8*)(smh + off + 8);
            union { uint4 u; half8 h; } bb; bb.u = bq[j];
            accA = __builtin_amdgcn_mfma_f32_32x32x16_f16(a0, bb.h, accA, 0, 0, 0);
            accB = __builtin_amdgcn_mfma_f32_32x32x16_f16(a1, bb.h, accB, 0, 0, 0);
            int ne = __builtin_amdgcn_readfirstlane((int)sW[it + 8 + j]);
            eq[j] = ne;
            bq[j] = bpack[(size_t)(ne & 4095) * 64 + lane];
        }
    }

    // ---- cross-half reduction in LDS (A tile dead); stride 33 = conflict-free ----
    __syncthreads();
    float* red = (float*)smh;             // 2 pairs x 64 lanes x 33 floats = 16.9 KB
    if (h == 1) {
        float* dst = red + ((size_t)(p * 64 + lane)) * 33;
        #pragma unroll
        for (int r = 0; r < 16; ++r) { dst[r] = accA[r]; dst[16 + r] = accB[r]; }
    }
    __syncthreads();
    if (h == 0) {
        const float* src = red + ((size_t)(p * 64 + lane)) * 33;
        #pragma unroll
        for (int r = 0; r < 16; ++r) { accA[r] += src[r]; accB[r] += src[16 + r]; }

        // growth + sum over q (lanes l, l^8, l^16) -> Uc (f16), octets 2p, 2p+1
        const int q = (lane & 31) >> 3, sy = lane & 7;
        const float mq = mp[c + 3 * q];
        const float sq = sp[c + 3 * q];
        const float hq = hp[c + 3 * q];
        const float i2s = 1.f / (2.f * sq * sq);
        #pragma unroll
        for (int oo = 0; oo < 2; ++oo) {
            const f32x16& acc = oo ? accB : accA;
            const int col = y0 + 16 * p + 8 * oo + sy;
            #pragma unroll
            for (int r = 0; r < 16; ++r) {
                float d = acc[r] - mq;
                float gg = (2.f * expf(-d * d * i2s) - 1.f) * hq;
                gg += __shfl_xor(gg, 8);
                gg += __shfl_xor(gg, 16);
                if ((lane & 24) == 0) {
                    int row = (r & 3) + ((r >> 2) << 3) + (g << 2);
                    Uc[((size_t)(b << 16) + ((x0 + row) << 8) + col) * 3 + c] = (f16)gg;
                }
            }
        }
    }
}

// ------- kernel 5: fused sobel+flow+mus + RT, PER-CHANNEL blocks (grid 64x12) -------
#define FTW 44
#define FSW 45
#define PLH (FSW * FTW)           // 1980 elems per plane
__global__ __launch_bounds__(256) void lenia_flowrt(
        const f16* __restrict__ Atr, const f16* __restrict__ Uc,
        float* __restrict__ out) {
    extern __shared__ char fraw[];
    f16*    ucp = (f16*)fraw;                    // [PLH]       uc, this channel
    f16*    atp = (f16*)(fraw + PLH * 2);        // [3][PLH]    A, all channels
    float2* muq = (float2*)(fraw + 8 * PLH);     // [PLH]       (dx, dy), this channel

    int bc = blockIdx.y;                         // 12: b*3+c
    int b = bc / 3, c = bc - b * 3;
    int t = blockIdx.x;                          // 64 tiles of 32x32
    int x0 = (t >> 3) << 5, y0 = (t & 7) << 5;
    const f16* A0 = Atr + (size_t)(b * 3) * 65536;
    const f16* Ub = Uc + ((size_t)b << 16) * 3;

    for (int idx = threadIdx.x; idx < FTW * FTW; idx += 256) {
        int si = idx / FTW, sj = idx - si * FTW;
        int gi = (x0 - 6 + si) & 255, gj = (y0 - 6 + sj) & 255;
        int pix = (gi << 8) + gj;
        int o = si * FSW + sj;
        ucp[o] = Ub[(size_t)pix * 3 + c];
        atp[o] = A0[pix];
        atp[PLH + o] = A0[65536 + pix];
        atp[2 * PLH + o] = A0[131072 + pix];
    }
    __syncthreads();

    // mus phase: 42x42 cells (this channel only)
    for (int idx = threadIdx.x; idx < 42 * 42; idx += 256) {
        int ci = idx / 42, cj = idx - ci * 42;
        int si = ci + 1, sj = cj + 1;
        int o = si * FSW + sj;
        int vx = x0 - 6 + si, vy = y0 - 6 + sj;
        float sx = (vx < 0 || vx > 255) ? 1e7f : 0.f;
        float syv = (vy < 0 || vy > 255) ? 1e7f : 0.f;

        float as[3][3];
        #pragma unroll
        for (int i = 0; i < 3; ++i)
            #pragma unroll
            for (int j = 0; j < 3; ++j) {
                int oo = o + (i - 1) * FSW + (j - 1);
                as[i][j] = (float)atp[oo] + (float)atp[PLH + oo] + (float)atp[2 * PLH + oo];
            }
        float gxA = ((as[2][0] + 2.f * as[2][1] + as[2][2])
                   - (as[0][0] + 2.f * as[0][1] + as[0][2])) * 0.125f;
        float gyA = ((as[0][2] + 2.f * as[1][2] + as[2][2])
                   - (as[0][0] + 2.f * as[1][0] + as[2][0])) * 0.125f;

        float u00 = ucp[o - FSW - 1], u01 = ucp[o - FSW], u02 = ucp[o - FSW + 1];
        float u10 = ucp[o - 1],                          u12 = ucp[o + 1];
        float u20 = ucp[o + FSW - 1], u21 = ucp[o + FSW], u22 = ucp[o + FSW + 1];
        float gx = ((u20 + 2.f * u21 + u22) - (u00 + 2.f * u01 + u02)) * 0.125f;
        float gy = ((u02 + 2.f * u12 + u22) - (u00 + 2.f * u10 + u20)) * 0.125f;
        float a = (float)atp[c * PLH + o];
        float alpha = fminf(a * a, 1.f);
        float Fx = gx * (1.f - alpha) - gxA * alpha;
        float Fy = gy * (1.f - alpha) - gyA * alpha;
        float dx = fminf(fmaxf(0.2f * Fx, -4.35f), 4.35f) + sx;
        float dy = fminf(fmaxf(0.2f * Fy, -4.35f), 4.35f) + syv;
        muq[o] = make_float2(dx, dy);
    }
    __syncthreads();

    // gather: thread = (x col tx, y quad tyg), this channel
    int tx = threadIdx.x & 31, tyg = threadIdx.x >> 5;
    int ty0 = tyg << 2;
    float a0 = 0.f, a1 = 0.f, a2 = 0.f, a3 = 0.f;
    const f16* ac = atp + c * PLH;

    for (int dxs = 0; dxs < 11; ++dxs) {
        float fdx = (float)(5 - dxs);
        int rowb = (tx + 1 + dxs) * FSW + (ty0 + 1);
        #pragma unroll
        for (int sjj = 0; sjj < 14; ++sjj) {
            float fdy = (float)(5 - sjj);
            float2 mu = muq[rowb + sjj];
            float av = (float)ac[rowb + sjj];
            float wx = fminf(fmaxf(1.15f - fabsf(fdx - mu.x), 0.f), 1.f);
            float awx = av * wx;
            float e0 = fdy - mu.y;
            a0 = fmaf(awx, fminf(fmaxf(1.15f - fabsf(e0), 0.f), 1.f), a0);
            a1 = fmaf(awx, fminf(fmaxf(1.15f - fabsf(e0 + 1.f), 0.f), 1.f), a1);
            a2 = fmaf(awx, fminf(fmaxf(1.15f - fabsf(e0 + 2.f), 0.f), 1.f), a2);
            a3 = fmaf(awx, fminf(fmaxf(1.15f - fabsf(e0 + 3.f), 0.f), 1.f), a3);
        }
    }
    const float inv = 1.0f / 1.69f;   // 1/(4*sigma^2)
    size_t ob = ((size_t)(b << 16) + ((x0 + tx) << 8) + (y0 + ty0)) * 3 + c;
    out[ob]     = a0 * inv;
    out[ob + 3] = a1 * inv;
    out[ob + 6] = a2 * inv;
    out[ob + 9] = a3 * inv;
}

extern "C" void kernel_launch(void* const* d_in, const int* in_sizes, int n_in,
                              void* d_out, int out_size, void* d_ws, size_t ws_size,
                              hipStream_t stream) {
    const float* A  = (const float*)d_in[0];
    const float* Kn = (const float*)d_in[1];
    const float* m  = (const float*)d_in[2];
    const float* s  = (const float*)d_in[3];
    const float* h  = (const float*)d_in[4];

    char* ws = (char*)d_ws;
    int*          radii = (int*)ws;                        // 16 B
    int*          nschd = (int*)(ws + 16);
    int*          rowr  = (int*)(ws + 64);                 // 267*4
    int2*         meta  = (int2*)(ws + 2048);              // 267*8
    int2*         meta2 = (int2*)(ws + 8192);              // 267*8
    unsigned int* sched = (unsigned int*)(ws + 16384);     // 12 KB
    f16*          Atr   = (f16*)(ws + 32768);              // 1.57 MB
    uint4*        bpack = (uint4*)(ws + 1605632);          // 2.19 MB
    f16*          Uc    = (f16*)(ws + 3793920);            // 1.57 MB -> ends 5.37 MB

    lenia_meta<<<3 * NROWS, 128, 0, stream>>>(Kn, meta, rowr);
    lenia_sched<<<3, 128, 0, stream>>>(meta, rowr, meta2, sched, nschd, radii);
    lenia_prep2<<<NBPK + 1024, 256, 0, stream>>>(Kn, A, meta2, bpack, Atr);
    lenia_conv<<<dim3(64, 12), 256, TROWS * ST * sizeof(f16), stream>>>(
        Atr, bpack, sched, nschd, radii, m, s, h, Uc);
    lenia_flowrt<<<dim3(64, 12), 256, 8 * PLH + PLH * 8, stream>>>(
        Atr, Uc, (float*)d_out);
}

// Round 15
// 70.525 us; speedup vs baseline: 1.2759x; 1.0549x over previous
//
#include <hip/hip_runtime.h>

// FlowLenia single step — MFMA implicit-GEMM convolution (f16), fused flow+RT.
// A:[4,1,256,256,3] f32, Kn:[256,256,12] f32, m/s/h:[12], c0/c1 = arange(12)%3.
// out nA:[4,1,256,256,3] f32.
//
// Conv: 512 thr = 8 waves = 4 K-quarters x 2 octet-pairs. Wave (qr,p) runs
// quarter qr of the schedule for octets {2p,2p+1} (1 B-load -> 2 MFMAs).
// 24 waves/CU (2x r14). Cross-quarter LDS reduction in the dead A-tile.

typedef _Float16 f16;
typedef __attribute__((ext_vector_type(8))) _Float16 half8;
typedef __attribute__((ext_vector_type(16))) float f32x16;

#define RMAX 44
#define NROWS 89                  // 2*RMAX+1
#define NDMAX 8
#define NFRAG (3*NROWS*NDMAX)     // real fragments; slot NFRAG = zeros
#define NBPK ((NFRAG + 4) / 4)    // bpack blocks (4 frags / 256-thr block)
#define ST 168                    // LDS row stride (f16), 21 half8 chunks
#define TROWS 120                 // 32 + 2*RMAX
#define SCHED_STRIDE 1024
#define KTHR 1e-7f

// ---------------- kernel 1: per-(c,di) dj bounds + per-row radius ----------------
__global__ __launch_bounds__(128) void lenia_meta(const float* __restrict__ Kn,
                                                  int2* __restrict__ meta,
                                                  int* __restrict__ rowr) {
    int blk = blockIdx.x;                 // 3*NROWS
    int c = blk / NROWS, ri = blk - c * NROWS;
    int di = ri - RMAX;
    int t = threadIdx.x;
    int dj = t - RMAX;
    int act = 0;
    if (t < NROWS) {
        size_t base = (size_t)(((di + 128) << 8) | (dj + 128)) * 12 + c;
        float k0 = Kn[base], k1 = Kn[base + 3], k2 = Kn[base + 6], k3 = Kn[base + 9];
        act = (fmaxf(fmaxf(k0, k1), fmaxf(k2, k3)) > KTHR) ? 1 : 0;
    }
    __shared__ int smn[128], smx[128];
    smn[t] = act ? dj : 1000;
    smx[t] = act ? dj : -1000;
    __syncthreads();
    for (int s = 64; s > 0; s >>= 1) {
        if (t < s) { smn[t] = min(smn[t], smn[t + s]); smx[t] = max(smx[t], smx[t + s]); }
        __syncthreads();
    }
    if (t == 0) {
        int jmn = smn[0], jmx = smx[0];
        if (jmx < jmn) { meta[blk] = make_int2(1, 0); rowr[blk] = 0; }
        else {
            meta[blk] = make_int2(jmn, jmx);
            rowr[blk] = max(abs(di), max(abs(jmn), abs(jmx)));
        }
    }
}

// ------------- kernel 2: chunk geometry + flat schedule (w/ LDS offsets) + radii -------------
__global__ __launch_bounds__(128) void lenia_sched(const int2* __restrict__ meta,
                                                   const int* __restrict__ rowr,
                                                   int2* __restrict__ meta2,
                                                   unsigned int* __restrict__ sched,
                                                   int* __restrict__ nsched,
                                                   int* __restrict__ radii) {
    int c = blockIdx.x;                   // 3 blocks
    int t = threadIdx.x;
    __shared__ int pre[NROWS], nds[NROWS], rmx[128];
    int nd = 0, d0 = 0;
    if (t < NROWS) {
        int2 bm = meta[c * NROWS + t];
        if (bm.y >= bm.x) {
            d0 = ((bm.x - 7) >> 3) << 3;          // delta0 <= jmn-7, mult of 8
            nd = ((bm.y + 7 - d0) >> 4) + 1;      // cover dj' = jmx for sy up to 7
        }
        meta2[c * NROWS + t] = make_int2(d0, nd);
        nds[t] = nd;
    }
    rmx[t] = (t < NROWS) ? rowr[c * NROWS + t] : 0;
    __syncthreads();
    for (int s = 64; s > 0; s >>= 1) {
        if (t < s) rmx[t] = max(rmx[t], rmx[t + s]);
        __syncthreads();
    }
    __shared__ int tot;
    if (t == 0) {
        radii[c] = rmx[0];
        int acc = 0;
        for (int i = 0; i < NROWS; ++i) { pre[i] = acc; acc += nds[i]; }
        tot = acc;
    }
    __syncthreads();
    if (t < NROWS && nd > 0) {
        int base = pre[t];
        for (int i = 0; i < nd; ++i) {
            int delta = d0 + 16 * i;
            unsigned int off = (unsigned int)(t * ST + delta + 128);   // 14 bits
            sched[c * SCHED_STRIDE + base + i] =
                (unsigned int)((c * NROWS + t) * NDMAX + i) | (off << 12);
        }
    }
    if (t == 0) {
        int ns = (tot + 31) & ~31;        // mult of 32 -> quarters are mult of 8
        unsigned int padoff = (unsigned int)(RMAX * ST + 128);
        for (int i = tot; i < ns + 48; ++i)       // pads: zero frag, valid lds addr
            sched[c * SCHED_STRIDE + i] = (unsigned int)NFRAG | (padoff << 12);
        nsched[c] = ns;
    }
}

// ------- kernel 3: FUSED bpack-from-Kn (blocks < NBPK) + A-transpose (rest) -------
__global__ __launch_bounds__(256) void lenia_prep2(const float* __restrict__ Kn,
                                                   const float* __restrict__ A,
                                                   const int2* __restrict__ meta2,
                                                   uint4* __restrict__ bpack,
                                                   f16* __restrict__ Atr) {
    int blk = blockIdx.x;
    if (blk < NBPK) {                     // ---- bpack part ----
        int fi = blk * 4 + (threadIdx.x >> 6);
        int l = threadIdx.x & 63;
        if (fi > NFRAG) return;
        union { f16 h[8]; uint4 u; } pk;
        if (fi == NFRAG) {
            pk.u = make_uint4(0, 0, 0, 0);
            bpack[(size_t)fi * 64 + l] = pk.u;
            return;
        }
        int c = fi / (NROWS * NDMAX);
        int rem = fi - c * (NROWS * NDMAX);
        int ri = rem >> 3, didx = rem & 7;
        int di = ri - RMAX;
        int delta = meta2[c * NROWS + ri].x + 16 * didx;
        int q = (l & 31) >> 3, sy = l & 7, g = l >> 5;
        int dj0 = delta + 8 * g - sy;     // in [-63, 71]: row-local, in-bounds
        const float* src = Kn + (size_t)(((di + 128) << 8) + (dj0 + 128)) * 12 + c + 3 * q;
        #pragma unroll
        for (int j = 0; j < 8; ++j) pk.h[j] = (f16)src[j * 12];
        bpack[(size_t)fi * 64 + l] = pk.u;
    } else {                              // ---- A-transpose part ----
        int px = (blk - NBPK) * 256 + threadIdx.x;   // 0..262143
        int b = px >> 16, rem = px & 65535;
        const float* ap = A + (size_t)px * 3;
        Atr[(size_t)(b * 3 + 0) * 65536 + rem] = (f16)ap[0];
        Atr[(size_t)(b * 3 + 1) * 65536 + rem] = (f16)ap[1];
        Atr[(size_t)(b * 3 + 2) * 65536 + rem] = (f16)ap[2];
    }
}

// ---------------- kernel 4: MFMA conv + growth -> Uc (f16, in ws) ----------------
// 512 thr = 8 waves; wave (qr = wid>>1, p = wid&1): schedule quarter qr,
// octets {2p, 2p+1}. 8-deep in-place B ring, scalar schedule. Cross-quarter
// LDS reduce (2 pairwise rounds), growth+store on qr==0 waves.
__global__ __launch_bounds__(512, 6) void lenia_conv(
        const f16* __restrict__ Atr, const uint4* __restrict__ bpack,
        const unsigned int* __restrict__ sched, const int* __restrict__ nsched,
        const int* __restrict__ radii,
        const float* __restrict__ mp, const float* __restrict__ sp,
        const float* __restrict__ hp, f16* __restrict__ Uc) {
    extern __shared__ f16 smh[];

    const int tid = threadIdx.x;
    const int bc = blockIdx.y;
    const int b = bc / 3, c = bc - b * 3;
    const int x0 = (blockIdx.x >> 3) << 5;
    const int y0 = (blockIdx.x & 7) << 5;

    const int R = __builtin_amdgcn_readfirstlane(min(max(radii[c], 1), RMAX));
    const int R8 = (R + 7) & ~7;
    const int colbase = y0 - R8 - 16;     // mult of 8
    const int rows = 32 + 2 * R;
    const f16* Ap = Atr + (size_t)(b * 3 + c) * 65536;

    {   // staging: half8 (16B) chunks; 21 chunks/row; 512 threads
        int nchunk = rows * 21;
        int tr = tid / 21, rem = tid - tr * 21;
        for (int ci = tid; ci < nchunk; ci += 512) {
            int gi = (x0 - R + tr) & 255;
            int gj = (colbase + rem * 8) & 255;   // mult of 8 -> never crosses wrap
            *(half8*)(smh + tr * ST + rem * 8) = *(const half8*)(Ap + (gi << 8) + gj);
            tr += 24; rem += 8;                   // +512 chunks = 24*21 + 8
            if (rem >= 21) { rem -= 21; ++tr; }
        }
    }
    __syncthreads();

    const int lane = tid & 63, wid = tid >> 6;    // 8 waves
    const int p = wid & 1, qr = wid >> 1;         // octet-pair p, quarter qr
    const int m = lane & 31, g = lane >> 5;
    // octet 2p base (octet 2p+1 = +8), incl. the -128 bias of sched offsets
    const int abase = (m + R - RMAX) * ST + 16 * p + R8 + 16 + 8 * g - 128;

    const int ns = __builtin_amdgcn_readfirstlane(nsched[c]);   // mult of 32
    const int nsQ = ns >> 2;                                    // mult of 8
    const unsigned int* sW = sched + c * SCHED_STRIDE + qr * nsQ;

    f32x16 accA, accB;                    // octet 2p / octet 2p+1 chains
    #pragma unroll
    for (int r = 0; r < 16; ++r) { accA[r] = 0.f; accB[r] = 0.f; }

    int eq[8];
    uint4 bq[8];
    #pragma unroll
    for (int j = 0; j < 8; ++j) {
        int e = __builtin_amdgcn_readfirstlane((int)sW[j]);
        eq[j] = e;
        bq[j] = bpack[(size_t)(e & 4095) * 64 + lane];
    }

    for (int it = 0; it < nsQ; it += 8) {
        #pragma unroll
        for (int j = 0; j < 8; ++j) {
            const int off = abase + (eq[j] >> 12);
            half8 a0 = *(const half8*)(smh + off);
            half8 a1 = *(const half8*)(smh + off + 8);
            union { uint4 u; half8 h; } bb; bb.u = bq[j];
            accA = __builtin_amdgcn_mfma_f32_32x32x16_f16(a0, bb.h, accA, 0, 0, 0);
            accB = __builtin_amdgcn_mfma_f32_32x32x16_f16(a1, bb.h, accB, 0, 0, 0);
            int ne = __builtin_amdgcn_readfirstlane((int)sW[it + 8 + j]);
            eq[j] = ne;
            bq[j] = bpack[(size_t)(ne & 4095) * 64 + lane];
        }
    }

    // ---- cross-quarter reduction in LDS (A tile dead); stride 33 = conflict-free ----
    __syncthreads();
    float* red = (float*)smh;             // max 4 groups x 64 lanes x 33 f32 = 33 KB
    if (qr >= 2) {                        // quarters 2,3 write
        float* dst = red + ((size_t)(((p << 1) + (qr - 2)) * 64 + lane)) * 33;
        #pragma unroll
        for (int r = 0; r < 16; ++r) { dst[r] = accA[r]; dst[16 + r] = accB[r]; }
    }
    __syncthreads();
    if (qr < 2) {                         // quarters 0,1 add
        const float* src = red + ((size_t)(((p << 1) + qr) * 64 + lane)) * 33;
        #pragma unroll
        for (int r = 0; r < 16; ++r) { accA[r] += src[r]; accB[r] += src[16 + r]; }
    }
    __syncthreads();
    if (qr == 1) {                        // quarter 1 writes combined
        float* dst = red + ((size_t)(p * 64 + lane)) * 33;
        #pragma unroll
        for (int r = 0; r < 16; ++r) { dst[r] = accA[r]; dst[16 + r] = accB[r]; }
    }
    __syncthreads();
    if (qr == 0) {
        const float* src = red + ((size_t)(p * 64 + lane)) * 33;
        #pragma unroll
        for (int r = 0; r < 16; ++r) { accA[r] += src[r]; accB[r] += src[16 + r]; }

        // growth + sum over q (lanes l, l^8, l^16) -> Uc (f16), octets 2p, 2p+1
        const int q = (lane & 31) >> 3, sy = lane & 7;
        const float mq = mp[c + 3 * q];
        const float sq = sp[c + 3 * q];
        const float hq = hp[c + 3 * q];
        const float i2s = 1.f / (2.f * sq * sq);
        #pragma unroll
        for (int oo = 0; oo < 2; ++oo) {
            const f32x16& acc = oo ? accB : accA;
            const int col = y0 + 16 * p + 8 * oo + sy;
            #pragma unroll
            for (int r = 0; r < 16; ++r) {
                float d = acc[r] - mq;
                float gg = (2.f * expf(-d * d * i2s) - 1.f) * hq;
                gg += __shfl_xor(gg, 8);
                gg += __shfl_xor(gg, 16);
                if ((lane & 24) == 0) {
                    int row = (r & 3) + ((r >> 2) << 3) + (g << 2);
                    Uc[((size_t)(b << 16) + ((x0 + row) << 8) + col) * 3 + c] = (f16)gg;
                }
            }
        }
    }
}

// ------- kernel 5: fused sobel+flow+mus + RT, PER-CHANNEL blocks (grid 64x12) -------
#define FTW 44
#define FSW 45
#define PLH (FSW * FTW)           // 1980 elems per plane
__global__ __launch_bounds__(256) void lenia_flowrt(
        const f16* __restrict__ Atr, const f16* __restrict__ Uc,
        float* __restrict__ out) {
    extern __shared__ char fraw[];
    f16*    ucp = (f16*)fraw;                    // [PLH]       uc, this channel
    f16*    atp = (f16*)(fraw + PLH * 2);        // [3][PLH]    A, all channels
    float2* muq = (float2*)(fraw + 8 * PLH);     // [PLH]       (dx, dy), this channel

    int bc = blockIdx.y;                         // 12: b*3+c
    int b = bc / 3, c = bc - b * 3;
    int t = blockIdx.x;                          // 64 tiles of 32x32
    int x0 = (t >> 3) << 5, y0 = (t & 7) << 5;
    const f16* A0 = Atr + (size_t)(b * 3) * 65536;
    const f16* Ub = Uc + ((size_t)b << 16) * 3;

    for (int idx = threadIdx.x; idx < FTW * FTW; idx += 256) {
        int si = idx / FTW, sj = idx - si * FTW;
        int gi = (x0 - 6 + si) & 255, gj = (y0 - 6 + sj) & 255;
        int pix = (gi << 8) + gj;
        int o = si * FSW + sj;
        ucp[o] = Ub[(size_t)pix * 3 + c];
        atp[o] = A0[pix];
        atp[PLH + o] = A0[65536 + pix];
        atp[2 * PLH + o] = A0[131072 + pix];
    }
    __syncthreads();

    // mus phase: 42x42 cells (this channel only)
    for (int idx = threadIdx.x; idx < 42 * 42; idx += 256) {
        int ci = idx / 42, cj = idx - ci * 42;
        int si = ci + 1, sj = cj + 1;
        int o = si * FSW + sj;
        int vx = x0 - 6 + si, vy = y0 - 6 + sj;
        float sx = (vx < 0 || vx > 255) ? 1e7f : 0.f;
        float syv = (vy < 0 || vy > 255) ? 1e7f : 0.f;

        float as[3][3];
        #pragma unroll
        for (int i = 0; i < 3; ++i)
            #pragma unroll
            for (int j = 0; j < 3; ++j) {
                int oo = o + (i - 1) * FSW + (j - 1);
                as[i][j] = (float)atp[oo] + (float)atp[PLH + oo] + (float)atp[2 * PLH + oo];
            }
        float gxA = ((as[2][0] + 2.f * as[2][1] + as[2][2])
                   - (as[0][0] + 2.f * as[0][1] + as[0][2])) * 0.125f;
        float gyA = ((as[0][2] + 2.f * as[1][2] + as[2][2])
                   - (as[0][0] + 2.f * as[1][0] + as[2][0])) * 0.125f;

        float u00 = ucp[o - FSW - 1], u01 = ucp[o - FSW], u02 = ucp[o - FSW + 1];
        float u10 = ucp[o - 1],                          u12 = ucp[o + 1];
        float u20 = ucp[o + FSW - 1], u21 = ucp[o + FSW], u22 = ucp[o + FSW + 1];
        float gx = ((u20 + 2.f * u21 + u22) - (u00 + 2.f * u01 + u02)) * 0.125f;
        float gy = ((u02 + 2.f * u12 + u22) - (u00 + 2.f * u10 + u20)) * 0.125f;
        float a = (float)atp[c * PLH + o];
        float alpha = fminf(a * a, 1.f);
        float Fx = gx * (1.f - alpha) - gxA * alpha;
        float Fy = gy * (1.f - alpha) - gyA * alpha;
        float dx = fminf(fmaxf(0.2f * Fx, -4.35f), 4.35f) + sx;
        float dy = fminf(fmaxf(0.2f * Fy, -4.35f), 4.35f) + syv;
        muq[o] = make_float2(dx, dy);
    }
    __syncthreads();

    // gather: thread = (x col tx, y quad tyg), this channel
    int tx = threadIdx.x & 31, tyg = threadIdx.x >> 5;
    int ty0 = tyg << 2;
    float a0 = 0.f, a1 = 0.f, a2 = 0.f, a3 = 0.f;
    const f16* ac = atp + c * PLH;

    for (int dxs = 0; dxs < 11; ++dxs) {
        float fdx = (float)(5 - dxs);
        int rowb = (tx + 1 + dxs) * FSW + (ty0 + 1);
        #pragma unroll
        for (int sjj = 0; sjj < 14; ++sjj) {
            float fdy = (float)(5 - sjj);
            float2 mu = muq[rowb + sjj];
            float av = (float)ac[rowb + sjj];
            float wx = fminf(fmaxf(1.15f - fabsf(fdx - mu.x), 0.f), 1.f);
            float awx = av * wx;
            float e0 = fdy - mu.y;
            a0 = fmaf(awx, fminf(fmaxf(1.15f - fabsf(e0), 0.f), 1.f), a0);
            a1 = fmaf(awx, fminf(fmaxf(1.15f - fabsf(e0 + 1.f), 0.f), 1.f), a1);
            a2 = fmaf(awx, fminf(fmaxf(1.15f - fabsf(e0 + 2.f), 0.f), 1.f), a2);
            a3 = fmaf(awx, fminf(fmaxf(1.15f - fabsf(e0 + 3.f), 0.f), 1.f), a3);
        }
    }
    const float inv = 1.0f / 1.69f;   // 1/(4*sigma^2)
    size_t ob = ((size_t)(b << 16) + ((x0 + tx) << 8) + (y0 + ty0)) * 3 + c;
    out[ob]     = a0 * inv;
    out[ob + 3] = a1 * inv;
    out[ob + 6] = a2 * inv;
    out[ob + 9] = a3 * inv;
}

extern "C" void kernel_launch(void* const* d_in, const int* in_sizes, int n_in,
                              void* d_out, int out_size, void* d_ws, size_t ws_size,
                              hipStream_t stream) {
    const float* A  = (const float*)d_in[0];
    const float* Kn = (const float*)d_in[1];
    const float* m  = (const float*)d_in[2];
    const float* s  = (const float*)d_in[3];
    const float* h  = (const float*)d_in[4];

    char* ws = (char*)d_ws;
    int*          radii = (int*)ws;                        // 16 B
    int*          nschd = (int*)(ws + 16);
    int*          rowr  = (int*)(ws + 64);                 // 267*4
    int2*         meta  = (int2*)(ws + 2048);              // 267*8
    int2*         meta2 = (int2*)(ws + 8192);              // 267*8
    unsigned int* sched = (unsigned int*)(ws + 16384);     // 12 KB
    f16*          Atr   = (f16*)(ws + 32768);              // 1.57 MB
    uint4*        bpack = (uint4*)(ws + 1605632);          // 2.19 MB
    f16*          Uc    = (f16*)(ws + 3793920);            // 1.57 MB -> ends 5.37 MB

    lenia_meta<<<3 * NROWS, 128, 0, stream>>>(Kn, meta, rowr);
    lenia_sched<<<3, 128, 0, stream>>>(meta, rowr, meta2, sched, nschd, radii);
    lenia_prep2<<<NBPK + 1024, 256, 0, stream>>>(Kn, A, meta2, bpack, Atr);
    lenia_conv<<<dim3(64, 12), 512, TROWS * ST * sizeof(f16), stream>>>(
        Atr, bpack, sched, nschd, radii, m, s, h, Uc);
    lenia_flowrt<<<dim3(64, 12), 256, 8 * PLH + PLH * 8, stream>>>(
        Atr, Uc, (float*)d_out);
}